// Round 14
// baseline (1320.632 us; speedup 1.0000x reference)
//
#include <hip/hip_runtime.h>
#include <math.h>

#define CC 512
#define NH 8
#define HD 64
#define TT 256

typedef __attribute__((ext_vector_type(8))) short short8v;
typedef __attribute__((ext_vector_type(4))) short short4v;
typedef __attribute__((ext_vector_type(4))) float f32x4;

__device__ inline unsigned short bfc(float f) {  // fp32 -> bf16, RNE
  unsigned u = __float_as_uint(f);
  return (unsigned short)((u + 0x7fffu + ((u >> 16) & 1u)) >> 16);
}
__device__ inline float b2f(unsigned short s) {
  return __uint_as_float((unsigned)s << 16);
}
// async global->LDS, 16B per lane; l must be the wave-uniform base.
__device__ inline void gld16(const void* g, void* l) {
  __builtin_amdgcn_global_load_lds(
      (const __attribute__((address_space(1))) unsigned int*)g,
      (__attribute__((address_space(3))) unsigned int*)l, 16, 0, 0);
}

// ---------------- prep: x=id_x; fb=bf16(frames); pb=bf16(id_prev) ------------
__global__ __launch_bounds__(256) void prep_k(const float* __restrict__ id_x,
    const float* __restrict__ frames, const float* __restrict__ id_prev,
    float* __restrict__ x, unsigned short* __restrict__ fb,
    unsigned short* __restrict__ pb) {
  int i = blockIdx.x * 256 + threadIdx.x;
  if (i < 262144) {
    ((float4*)x)[i] = ((const float4*)id_x)[i];
  } else if (i < 786432) {
    int j = i - 262144;
    float4 f = ((const float4*)frames)[j];
    ushort4 o; o.x = bfc(f.x); o.y = bfc(f.y); o.z = bfc(f.z); o.w = bfc(f.w);
    ((ushort4*)fb)[j] = o;
  } else {
    int j = i - 786432;
    float4 f = ((const float4*)id_prev)[j];
    ushort4 o; o.x = bfc(f.x); o.y = bfc(f.y); o.z = bfc(f.z); o.w = bfc(f.w);
    ((ushort4*)pb)[j] = o;
  }
}

// ---------------- LayerNorm: one WAVE per row (no LDS, no barriers) ----------
__global__ __launch_bounds__(256) void ln_bf(const float* __restrict__ in,
    unsigned short* __restrict__ out, const float* __restrict__ g, const float* __restrict__ b) {
  int row = (blockIdx.x << 2) + (threadIdx.x >> 6), lane = threadIdx.x & 63;
  const float* r = in + (size_t)row * CC;
  float4 v0 = *(const float4*)(r + (lane << 2));
  float4 v1 = *(const float4*)(r + 256 + (lane << 2));
  float s = v0.x + v0.y + v0.z + v0.w + v1.x + v1.y + v1.z + v1.w;
  #pragma unroll
  for (int o = 32; o; o >>= 1) s += __shfl_xor(s, o);
  float mu = s * (1.0f / CC);
  float d0x = v0.x - mu, d0y = v0.y - mu, d0z = v0.z - mu, d0w = v0.w - mu;
  float d1x = v1.x - mu, d1y = v1.y - mu, d1z = v1.z - mu, d1w = v1.w - mu;
  float sq = d0x*d0x + d0y*d0y + d0z*d0z + d0w*d0w + d1x*d1x + d1y*d1y + d1z*d1z + d1w*d1w;
  #pragma unroll
  for (int o = 32; o; o >>= 1) sq += __shfl_xor(sq, o);
  float inv = rsqrtf(sq * (1.0f / CC) + 1e-5f);
  float4 g0 = *(const float4*)(g + (lane << 2)), g1 = *(const float4*)(g + 256 + (lane << 2));
  float4 b0 = *(const float4*)(b + (lane << 2)), b1 = *(const float4*)(b + 256 + (lane << 2));
  ushort4 o0, o1;
  o0.x = bfc(d0x*inv*g0.x + b0.x); o0.y = bfc(d0y*inv*g0.y + b0.y);
  o0.z = bfc(d0z*inv*g0.z + b0.z); o0.w = bfc(d0w*inv*g0.w + b0.w);
  o1.x = bfc(d1x*inv*g1.x + b1.x); o1.y = bfc(d1y*inv*g1.y + b1.y);
  o1.z = bfc(d1z*inv*g1.z + b1.z); o1.w = bfc(d1w*inv*g1.w + b1.w);
  *(ushort4*)(out + (size_t)row * CC + (lane << 2)) = o0;
  *(ushort4*)(out + (size_t)row * CC + 256 + (lane << 2)) = o1;
}

__global__ __launch_bounds__(256) void ln_final(const float* __restrict__ in,
    float* __restrict__ out, const float* __restrict__ g, const float* __restrict__ b) {
  int row = (blockIdx.x << 2) + (threadIdx.x >> 6), lane = threadIdx.x & 63;
  const float* r = in + (size_t)row * CC;
  float4 v0 = *(const float4*)(r + (lane << 2));
  float4 v1 = *(const float4*)(r + 256 + (lane << 2));
  float s = v0.x + v0.y + v0.z + v0.w + v1.x + v1.y + v1.z + v1.w;
  #pragma unroll
  for (int o = 32; o; o >>= 1) s += __shfl_xor(s, o);
  float mu = s * (1.0f / CC);
  float d0x = v0.x - mu, d0y = v0.y - mu, d0z = v0.z - mu, d0w = v0.w - mu;
  float d1x = v1.x - mu, d1y = v1.y - mu, d1z = v1.z - mu, d1w = v1.w - mu;
  float sq = d0x*d0x + d0y*d0y + d0z*d0z + d0w*d0w + d1x*d1x + d1y*d1y + d1z*d1z + d1w*d1w;
  #pragma unroll
  for (int o = 32; o; o >>= 1) sq += __shfl_xor(sq, o);
  float inv = rsqrtf(sq * (1.0f / CC) + 1e-5f);
  float4 g0 = *(const float4*)(g + (lane << 2)), g1 = *(const float4*)(g + 256 + (lane << 2));
  float4 b0 = *(const float4*)(b + (lane << 2)), b1 = *(const float4*)(b + 256 + (lane << 2));
  float4 o0, o1;
  o0.x = d0x*inv*g0.x + b0.x; o0.y = d0y*inv*g0.y + b0.y;
  o0.z = d0z*inv*g0.z + b0.z; o0.w = d0w*inv*g0.w + b0.w;
  o1.x = d1x*inv*g1.x + b1.x; o1.y = d1y*inv*g1.y + b1.y;
  o1.z = d1z*inv*g1.z + b1.z; o1.w = d1w*inv*g1.w + b1.w;
  *(float4*)(out + (size_t)row * CC + (lane << 2)) = o0;
  *(float4*)(out + (size_t)row * CC + 256 + (lane << 2)) = o1;
}

// LNf then LN1-of-next-layer: x fp32, xb bf16, h bf16 — all wave-local
__global__ __launch_bounds__(256) void ln_chain(const float* __restrict__ in,
    float* __restrict__ xout, unsigned short* __restrict__ xb,
    const float* __restrict__ gf, const float* __restrict__ bf,
    const float* __restrict__ g1, const float* __restrict__ b1,
    unsigned short* __restrict__ hout) {
  int row = (blockIdx.x << 2) + (threadIdx.x >> 6), lane = threadIdx.x & 63;
  const float* r = in + (size_t)row * CC;
  float4 v0 = *(const float4*)(r + (lane << 2));
  float4 v1 = *(const float4*)(r + 256 + (lane << 2));
  float s = v0.x + v0.y + v0.z + v0.w + v1.x + v1.y + v1.z + v1.w;
  #pragma unroll
  for (int o = 32; o; o >>= 1) s += __shfl_xor(s, o);
  float mu = s * (1.0f / CC);
  float d0x = v0.x - mu, d0y = v0.y - mu, d0z = v0.z - mu, d0w = v0.w - mu;
  float d1x = v1.x - mu, d1y = v1.y - mu, d1z = v1.z - mu, d1w = v1.w - mu;
  float sq = d0x*d0x + d0y*d0y + d0z*d0z + d0w*d0w + d1x*d1x + d1y*d1y + d1z*d1z + d1w*d1w;
  #pragma unroll
  for (int o = 32; o; o >>= 1) sq += __shfl_xor(sq, o);
  float inv = rsqrtf(sq * (1.0f / CC) + 1e-5f);
  float4 g0 = *(const float4*)(gf + (lane << 2)), g1v = *(const float4*)(gf + 256 + (lane << 2));
  float4 b0 = *(const float4*)(bf + (lane << 2)), b1v = *(const float4*)(bf + 256 + (lane << 2));
  float4 x0, x1;
  x0.x = d0x*inv*g0.x + b0.x; x0.y = d0y*inv*g0.y + b0.y;
  x0.z = d0z*inv*g0.z + b0.z; x0.w = d0w*inv*g0.w + b0.w;
  x1.x = d1x*inv*g1v.x + b1v.x; x1.y = d1y*inv*g1v.y + b1v.y;
  x1.z = d1z*inv*g1v.z + b1v.z; x1.w = d1w*inv*g1v.w + b1v.w;
  *(float4*)(xout + (size_t)row * CC + (lane << 2)) = x0;
  *(float4*)(xout + (size_t)row * CC + 256 + (lane << 2)) = x1;
  ushort4 xb0, xb1;
  xb0.x = bfc(x0.x); xb0.y = bfc(x0.y); xb0.z = bfc(x0.z); xb0.w = bfc(x0.w);
  xb1.x = bfc(x1.x); xb1.y = bfc(x1.y); xb1.z = bfc(x1.z); xb1.w = bfc(x1.w);
  *(ushort4*)(xb + (size_t)row * CC + (lane << 2)) = xb0;
  *(ushort4*)(xb + (size_t)row * CC + 256 + (lane << 2)) = xb1;
  // second LN
  float s2 = x0.x + x0.y + x0.z + x0.w + x1.x + x1.y + x1.z + x1.w;
  #pragma unroll
  for (int o = 32; o; o >>= 1) s2 += __shfl_xor(s2, o);
  float mu2 = s2 * (1.0f / CC);
  float e0x = x0.x - mu2, e0y = x0.y - mu2, e0z = x0.z - mu2, e0w = x0.w - mu2;
  float e1x = x1.x - mu2, e1y = x1.y - mu2, e1z = x1.z - mu2, e1w = x1.w - mu2;
  float sq2 = e0x*e0x + e0y*e0y + e0z*e0z + e0w*e0w + e1x*e1x + e1y*e1y + e1z*e1z + e1w*e1w;
  #pragma unroll
  for (int o = 32; o; o >>= 1) sq2 += __shfl_xor(sq2, o);
  float inv2 = rsqrtf(sq2 * (1.0f / CC) + 1e-5f);
  float4 h0 = *(const float4*)(g1 + (lane << 2)), h1 = *(const float4*)(g1 + 256 + (lane << 2));
  float4 c0 = *(const float4*)(b1 + (lane << 2)), c1 = *(const float4*)(b1 + 256 + (lane << 2));
  ushort4 ho0, ho1;
  ho0.x = bfc(e0x*inv2*h0.x + c0.x); ho0.y = bfc(e0y*inv2*h0.y + c0.y);
  ho0.z = bfc(e0z*inv2*h0.z + c0.z); ho0.w = bfc(e0w*inv2*h0.w + c0.w);
  ho1.x = bfc(e1x*inv2*h1.x + c1.x); ho1.y = bfc(e1y*inv2*h1.y + c1.y);
  ho1.z = bfc(e1z*inv2*h1.z + c1.z); ho1.w = bfc(e1w*inv2*h1.w + c1.w);
  *(ushort4*)(hout + (size_t)row * CC + (lane << 2)) = ho0;
  *(ushort4*)(hout + (size_t)row * CC + 256 + (lane << 2)) = ho1;
}

// ---------------- bf16 MFMA GEMM; B transposed+converted from fp32 W[K][N] ---
// A bf16 [M][K] via gld16 double-buffer; B: per K-step each thread reads 4
// fp32 rows x 4 cols of W, converts, ds_write_b64 transposed into swizzled Bs.
// T14 split: loads(t+1) before compute(t), writes after.
template<int BM, int GELU, int RES, int OUTBF, int QSC>
__global__ __launch_bounds__(256) void gemm_bf(
    const unsigned short* __restrict__ A, const float* __restrict__ Wf,
    const float* __restrict__ bias,
    void* __restrict__ outp, const float* __restrict__ res, int M, int N, int K) {
  __shared__ __align__(16) unsigned short As[2][BM * 64];
  __shared__ __align__(16) unsigned short Bs[2][64 * 64];
  const int tid = threadIdx.x, lane = tid & 63, wid = tid >> 6;
  const int bm = blockIdx.y * BM, bn = blockIdx.x << 6;
  const int wm = (wid >> 1) * (BM / 2), wn = (wid & 1) << 5;
  constexpr int MF = BM / 32;
  f32x4 acc[MF][2] = {};
  const int fr = lane & 15, fq = lane >> 4;
  const int srow_a = tid >> 3, sgc = tid & 7;
  const int kkb = (tid >> 4) << 2, bn0 = (tid & 15) << 2;  // B staging coords

  float4 breg[4];
  auto loadB = [&](int k0) {
    #pragma unroll
    for (int i = 0; i < 4; i++)
      breg[i] = *(const float4*)(Wf + (size_t)(k0 + kkb + i) * N + bn + bn0);
  };
  auto writeB = [&](int buf) {
    #pragma unroll
    for (int j = 0; j < 4; j++) {
      int n = bn0 + j;
      short4v v;
      v[0] = (short)bfc(((const float*)&breg[0])[j]);
      v[1] = (short)bfc(((const float*)&breg[1])[j]);
      v[2] = (short)bfc(((const float*)&breg[2])[j]);
      v[3] = (short)bfc(((const float*)&breg[3])[j]);
      *(short4v*)((char*)Bs[buf] + (((n << 7) + (kkb << 1)) ^ ((n & 7) << 4))) = v;
    }
  };
  auto stageA = [&](int buf, int k0) {
    #pragma unroll
    for (int i = 0; i < BM / 32; i++) {
      int row = srow_a + (i << 5);
      int gcs = sgc ^ (row & 7);
      gld16(A + (size_t)(bm + row) * K + k0 + (gcs << 3),
            (char*)As[buf] + (i << 12) + (wid << 10));
    }
  };

  loadB(0);
  stageA(0, 0);
  writeB(0);
  __syncthreads();
  int cur = 0;
  for (int k0 = 0; k0 < K; k0 += 64) {
    bool more = (k0 + 64 < K);
    if (more) { loadB(k0 + 64); stageA(cur ^ 1, k0 + 64); }
    short8v af[MF][2], bf2[2][2];
    #pragma unroll
    for (int mf = 0; mf < MF; mf++)
      #pragma unroll
      for (int ks = 0; ks < 2; ks++) {
        int r = wm + mf * 16 + fr;
        int c = (ks << 2) + fq;
        af[mf][ks] = *(const short8v*)((const char*)As[cur] + ((((r << 7) + (c << 4))) ^ ((r & 7) << 4)));
      }
    #pragma unroll
    for (int nf = 0; nf < 2; nf++)
      #pragma unroll
      for (int ks = 0; ks < 2; ks++) {
        int r = wn + nf * 16 + fr;
        int c = (ks << 2) + fq;
        bf2[nf][ks] = *(const short8v*)((const char*)Bs[cur] + ((((r << 7) + (c << 4))) ^ ((r & 7) << 4)));
      }
    #pragma unroll
    for (int mf = 0; mf < MF; mf++)
      #pragma unroll
      for (int nf = 0; nf < 2; nf++) {
        acc[mf][nf] = __builtin_amdgcn_mfma_f32_16x16x32_bf16(af[mf][0], bf2[nf][0], acc[mf][nf], 0, 0, 0);
        acc[mf][nf] = __builtin_amdgcn_mfma_f32_16x16x32_bf16(af[mf][1], bf2[nf][1], acc[mf][nf], 0, 0, 0);
      }
    if (more) writeB(cur ^ 1);
    __syncthreads();
    cur ^= 1;
  }
  #pragma unroll
  for (int mf = 0; mf < MF; mf++)
    #pragma unroll
    for (int nf = 0; nf < 2; nf++) {
      int col = bn + wn + nf * 16 + fr;
      float bia = bias[col];
      #pragma unroll
      for (int rr = 0; rr < 4; rr++) {
        int row = bm + wm + mf * 16 + fq * 4 + rr;
        float vv = acc[mf][nf][rr] + bia;
        if (GELU) vv = 0.5f * vv * (1.0f + erff(vv * 0.70710678118654752f));
        if (RES)  vv += res[(size_t)row * N + col];
        if (QSC)  vv *= 0.125f;
        if (OUTBF) ((unsigned short*)outp)[(size_t)row * N + col] = bfc(vv);
        else       ((float*)outp)[(size_t)row * N + col] = vv;
      }
    }
}

// ---------------- merged q-proj + kv-proj, B from fp32 Wq/Wk/Wv --------------
// blocks [0,256): q = (hb@Wq + bq)*0.125 -> qbuf; [256,..): kv -> kvb [Mkv][1024]
__global__ __launch_bounds__(256) void gemm_qkv(
    const unsigned short* __restrict__ hb, const float* __restrict__ Wq,
    const float* __restrict__ bq,
    const unsigned short* __restrict__ kvA, const float* __restrict__ Wk,
    const float* __restrict__ Wv,
    const float* __restrict__ bk, const float* __restrict__ bv,
    unsigned short* __restrict__ qout, unsigned short* __restrict__ kvout) {
  const int tid = threadIdx.x, lane = tid & 63, wid = tid >> 6;
  int bid = blockIdx.x;
  const unsigned short* A;
  const float *Wf, *bias;
  unsigned short* outp;
  int bm, bn, N, wcol;
  bool isq = bid < 256;
  if (isq) {
    A = hb; Wf = Wq; bias = bq; outp = qout; N = 512;
    bm = (bid >> 3) << 6; bn = (bid & 7) << 6; wcol = bn;
  } else {
    int t = bid - 256;
    A = kvA; outp = kvout; N = 1024;
    bm = (t >> 4) << 6; bn = (t & 15) << 6;
    Wf = (bn < 512) ? Wk : Wv;
    bias = (bn < 512) ? bk : bv;
    wcol = bn & 511;
  }
  __shared__ __align__(16) unsigned short As[2][64 * 64];
  __shared__ __align__(16) unsigned short Bs[2][64 * 64];
  const int wm = (wid >> 1) << 5, wn = (wid & 1) << 5;
  f32x4 acc[2][2] = {};
  const int fr = lane & 15, fq = lane >> 4;
  const int srow_a = tid >> 3, sgc = tid & 7;
  const int kkb = (tid >> 4) << 2, bn0 = (tid & 15) << 2;
  float4 breg[4];
  auto loadB = [&](int k0) {
    #pragma unroll
    for (int i = 0; i < 4; i++)
      breg[i] = *(const float4*)(Wf + (size_t)(k0 + kkb + i) * 512 + wcol + bn0);
  };
  auto writeB = [&](int buf) {
    #pragma unroll
    for (int j = 0; j < 4; j++) {
      int n = bn0 + j;
      short4v v;
      v[0] = (short)bfc(((const float*)&breg[0])[j]);
      v[1] = (short)bfc(((const float*)&breg[1])[j]);
      v[2] = (short)bfc(((const float*)&breg[2])[j]);
      v[3] = (short)bfc(((const float*)&breg[3])[j]);
      *(short4v*)((char*)Bs[buf] + (((n << 7) + (kkb << 1)) ^ ((n & 7) << 4))) = v;
    }
  };
  auto stageA = [&](int buf, int k0) {
    #pragma unroll
    for (int i = 0; i < 2; i++) {
      int row = srow_a + (i << 5);
      int gcs = sgc ^ (row & 7);
      gld16(A + (size_t)(bm + row) * 512 + k0 + (gcs << 3),
            (char*)As[buf] + (i << 12) + (wid << 10));
    }
  };
  loadB(0);
  stageA(0, 0);
  writeB(0);
  __syncthreads();
  int cur = 0;
  for (int k0 = 0; k0 < 512; k0 += 64) {
    bool more = (k0 + 64 < 512);
    if (more) { loadB(k0 + 64); stageA(cur ^ 1, k0 + 64); }
    short8v af[2][2], bf2[2][2];
    #pragma unroll
    for (int mf = 0; mf < 2; mf++)
      #pragma unroll
      for (int ks = 0; ks < 2; ks++) {
        int r = wm + mf * 16 + fr;
        int c = (ks << 2) + fq;
        af[mf][ks] = *(const short8v*)((const char*)As[cur] + ((((r << 7) + (c << 4))) ^ ((r & 7) << 4)));
        int r2 = wn + mf * 16 + fr;
        bf2[mf][ks] = *(const short8v*)((const char*)Bs[cur] + ((((r2 << 7) + (c << 4))) ^ ((r2 & 7) << 4)));
      }
    #pragma unroll
    for (int mf = 0; mf < 2; mf++)
      #pragma unroll
      for (int nf = 0; nf < 2; nf++) {
        acc[mf][nf] = __builtin_amdgcn_mfma_f32_16x16x32_bf16(af[mf][0], bf2[nf][0], acc[mf][nf], 0, 0, 0);
        acc[mf][nf] = __builtin_amdgcn_mfma_f32_16x16x32_bf16(af[mf][1], bf2[nf][1], acc[mf][nf], 0, 0, 0);
      }
    if (more) writeB(cur ^ 1);
    __syncthreads();
    cur ^= 1;
  }
  #pragma unroll
  for (int mf = 0; mf < 2; mf++)
    #pragma unroll
    for (int nf = 0; nf < 2; nf++) {
      int col = bn + wn + nf * 16 + fr;
      float bia = bias[(col & 511)];
      #pragma unroll
      for (int rr = 0; rr < 4; rr++) {
        int row = bm + wm + mf * 16 + fq * 4 + rr;
        float vv = acc[mf][nf][rr] + bia;
        if (isq) vv *= 0.125f;
        outp[(size_t)row * N + col] = bfc(vv);
      }
    }
}

// ---------------- MFMA attention: 8 q-rows/block, double-buffered K tiles ----
template<int CAUSAL, int TOPK, int TSK>
__global__ __launch_bounds__(512, 4) void attn_m(
    const unsigned short* __restrict__ qb, const unsigned short* __restrict__ kv,
    unsigned short* __restrict__ yb) {
  constexpr int NT = TSK / 64;
  constexpr int NKC = TSK / 128;
  constexpr int SST = TSK + 8;
  constexpr int SBYTES = 8 * SST * 4;
  __shared__ __align__(16) char sm[SBYTES + 32768 + 2048];
  float* S = (float*)sm;
  char* KsB = sm + SBYTES;            // 2 x 16KB K tile buffers
  char* Qs  = sm + SBYTES + 32768;    // 2KB (rows 8-15 zero)
  float* swt = (float*)KsB;                              // alias: 8x128 f32
  unsigned short* kidx = (unsigned short*)(KsB + 4096);  // alias: 8x128 u16
  int tid = threadIdx.x, lane = tid & 63, wid = tid >> 6;
  int bid = blockIdx.x;
  int swz = ((bid & 7) << 8) | (bid >> 3);  // 2048 blocks, bijective XCD swizzle
  int b = swz >> 8, h = (swz >> 5) & 7, q0 = (swz & 31) << 3;
  if (tid < 64) {
    int row = tid >> 3, sp = tid & 7;
    gld16(qb + (size_t)((b << 8) + q0 + row) * CC + (h << 6) + ((sp ^ (row & 7)) << 3),
          Qs);
  } else if (tid < 128) {
    short8v z = {0, 0, 0, 0, 0, 0, 0, 0};
    *(short8v*)(Qs + (tid << 4)) = z;
  }
  const unsigned short* kgb = kv + (size_t)b * TSK * 1024 + (h << 6);
  int nte = NKC;
  if (CAUSAL) { int ub = (q0 + 8 + 127) >> 7; nte = ub < NKC ? ub : NKC; }
  auto stageK = [&](int buf, int t) {
    #pragma unroll
    for (int j = 0; j < 2; j++) {
      int s = (wid << 7) + (j << 6) + lane;
      int row = s >> 3, sp = s & 7;
      gld16(kgb + (size_t)((t << 7) + row) * 1024 + ((sp ^ (row & 7)) << 3),
            KsB + (buf << 14) + (wid << 11) + (j << 10));
    }
  };
  stageK(0, 0);
  __syncthreads();
  short8v aF[2];
  {
    int r = lane & 15, kq2 = lane >> 4;
    #pragma unroll
    for (int kc2 = 0; kc2 < 2; kc2++)
      aF[kc2] = *(const short8v*)(Qs +
                 (((r << 7) + (kc2 << 6) + (kq2 << 4)) ^ ((r & 7) << 4)));
  }
  int cur = 0;
  for (int t = 0; t < nte; t++) {
    if (t + 1 < nte) stageK(cur ^ 1, t + 1);
    int kq2 = lane >> 4;
    f32x4 acc = {};
    int key16 = (wid << 4) + (lane & 15);
    #pragma unroll
    for (int kc2 = 0; kc2 < 2; kc2++) {
      short8v bF = *(const short8v*)(KsB + (cur << 14) +
                    (((key16 << 7) + (kc2 << 6) + (kq2 << 4)) ^ ((key16 & 7) << 4)));
      acc = __builtin_amdgcn_mfma_f32_16x16x32_bf16(aF[kc2], bF, acc, 0, 0, 0);
    }
    if (kq2 < 2) {  // valid q rows 0-7 live in fq 0,1
      int col = (t << 7) + key16;
      #pragma unroll
      for (int r = 0; r < 4; r++)
        S[(kq2 * 4 + r) * SST + col] = acc[r];
    }
    __syncthreads();
    cur ^= 1;
  }
  // ---- per-wave: one row select/softmax + PV gather (Ks region now dead) ----
  int row = wid;
  int qi = q0 + row;
  int jmax = CAUSAL ? (qi + 1) : TSK;
  const unsigned short* vgb = kv + (size_t)b * TSK * 1024 + 512 + (h << 6) + lane;
  float sc[NT];
  float lmax = -3.0e38f;
  #pragma unroll
  for (int tt = 0; tt < NT; tt++) {
    int key = lane + (tt << 6);
    float v = (!CAUSAL || key < jmax) ? S[row * SST + key] : -3.0e38f;
    sc[tt] = v;
    lmax = fmaxf(lmax, v);
  }
  float mx = lmax;
  #pragma unroll
  for (int o = 32; o; o >>= 1) mx = fmaxf(mx, __shfl_xor(mx, o));
  float oacc = 0.f;
  if (TOPK) {
    unsigned key[NT];
    #pragma unroll
    for (int tt = 0; tt < NT; tt++) {
      unsigned u = __float_as_uint(sc[tt]);
      key[tt] = (u & 0x80000000u) ? ~u : (u | 0x80000000u);
    }
    unsigned prefix = 0u;
    for (int bit = 31; bit >= 0; bit--) {   // early exit when kept set exact
      unsigned cand = prefix | (1u << bit);
      int cnt = 0;
      #pragma unroll
      for (int tt = 0; tt < NT; tt++)
        cnt += __popcll(__ballot(key[tt] >= cand));
      if (cnt >= 64) {
        prefix = cand;
        if (cnt == 64) break;
      }
    }
    float wvv[NT];
    float psum = 0.f;
    int basec = 0;
    #pragma unroll
    for (int tt = 0; tt < NT; tt++) {
      bool keep = key[tt] >= prefix;
      float wv = keep ? exp2f((sc[tt] - mx) * 1.4426950408889634f) : 0.f;
      wvv[tt] = wv;
      psum += wv;
      unsigned long long mask = __ballot(keep);
      if (keep) {
        int pos = basec + (int)__popcll(mask & ((1ull << lane) - 1ull));
        if (pos < 128) {
          kidx[(row << 7) + pos] = (unsigned short)(lane + (tt << 6));
          swt[(row << 7) + pos] = wv;
        }
      }
      basec += (int)__popcll(mask);
    }
    #pragma unroll
    for (int o = 32; o; o >>= 1) psum += __shfl_xor(psum, o);
    float inv = 1.0f / psum;
    int nk = basec;
    if (nk <= 128) {
      float a0 = 0.f, a1 = 0.f, a2 = 0.f, a3 = 0.f;
      int i = 0;
      for (; i + 3 < nk; i += 4) {
        a0 += swt[(row << 7) + i]     * b2f(vgb[(size_t)kidx[(row << 7) + i] * 1024]);
        a1 += swt[(row << 7) + i + 1] * b2f(vgb[(size_t)kidx[(row << 7) + i + 1] * 1024]);
        a2 += swt[(row << 7) + i + 2] * b2f(vgb[(size_t)kidx[(row << 7) + i + 2] * 1024]);
        a3 += swt[(row << 7) + i + 3] * b2f(vgb[(size_t)kidx[(row << 7) + i + 3] * 1024]);
      }
      for (; i < nk; i++) a0 += swt[(row << 7) + i] * b2f(vgb[(size_t)kidx[(row << 7) + i] * 1024]);
      oacc = (a0 + a1 + a2 + a3) * inv;
    } else {  // pathological tie overflow: full scan via S
      #pragma unroll
      for (int tt = 0; tt < NT; tt++)
        S[row * SST + lane + (tt << 6)] = wvv[tt];
      float a0 = 0.f, a1 = 0.f;
      for (int j = 0; j + 1 < TSK; j += 2) {
        a0 += S[row * SST + j]     * b2f(vgb[(size_t)j * 1024]);
        a1 += S[row * SST + j + 1] * b2f(vgb[(size_t)(j + 1) * 1024]);
      }
      oacc = (a0 + a1) * inv;
    }
  } else {
    float psum = 0.f;
    #pragma unroll
    for (int tt = 0; tt < NT; tt++) {
      int keyj = lane + (tt << 6);
      float wv = (keyj < jmax) ? exp2f((sc[tt] - mx) * 1.4426950408889634f) : 0.f;
      S[row * SST + keyj] = wv;
      psum += wv;
    }
    #pragma unroll
    for (int o = 32; o; o >>= 1) psum += __shfl_xor(psum, o);
    float inv = 1.0f / psum;
    float a0 = 0.f, a1 = 0.f, a2 = 0.f, a3 = 0.f;
    int j = 0;
    for (; j + 3 < jmax; j += 4) {
      a0 += S[row * SST + j]     * b2f(vgb[(size_t)j * 1024]);
      a1 += S[row * SST + j + 1] * b2f(vgb[(size_t)(j + 1) * 1024]);
      a2 += S[row * SST + j + 2] * b2f(vgb[(size_t)(j + 2) * 1024]);
      a3 += S[row * SST + j + 3] * b2f(vgb[(size_t)(j + 3) * 1024]);
    }
    for (; j < jmax; j++) a0 += S[row * SST + j] * b2f(vgb[(size_t)j * 1024]);
    oacc = (a0 + a1 + a2 + a3) * inv;
  }
  yb[(size_t)((b << 8) + qi) * CC + (h << 6) + lane] = bfc(oacc);
}

extern "C" void kernel_launch(void* const* d_in, const int* in_sizes, int n_in,
                              void* d_out, int out_size, void* d_ws, size_t ws_size,
                              hipStream_t stream) {
  const float* id_x    = (const float*)d_in[0];
  const float* id_prev = (const float*)d_in[1];
  const float* frames  = (const float*)d_in[2];
  const float* Wq = (const float*)d_in[3];  const float* bq = (const float*)d_in[4];
  const float* Wk = (const float*)d_in[5];  const float* bk = (const float*)d_in[6];
  const float* Wv = (const float*)d_in[7];  const float* bv = (const float*)d_in[8];
  const float* Wo = (const float*)d_in[9];  const float* bo = (const float*)d_in[10];
  const float* W1 = (const float*)d_in[11]; const float* b1 = (const float*)d_in[12];
  const float* W2 = (const float*)d_in[13]; const float* b2 = (const float*)d_in[14];
  const float* l1g = (const float*)d_in[15]; const float* l1b = (const float*)d_in[16];
  const float* l2g = (const float*)d_in[17]; const float* l2b = (const float*)d_in[18];
  const float* lfg = (const float*)d_in[19]; const float* lfb = (const float*)d_in[20];

  float* x = (float*)d_out;
  char* W  = (char*)d_ws;
  unsigned short* qbuf = (unsigned short*)W;                        // 2MB bf16 q (pre-scaled)
  unsigned short* kvb  = (unsigned short*)(W + ((size_t)4  << 20)); // 8MB packed K|V
  unsigned short* m1b  = (unsigned short*)(W + ((size_t)4  << 20)); // 8MB, alias kv
  unsigned short* hb   = (unsigned short*)(W + ((size_t)12 << 20)); // 2MB
  unsigned short* ybf  = (unsigned short*)(W + ((size_t)14 << 20)); // 2MB
  unsigned short* xb   = (unsigned short*)(W + ((size_t)16 << 20)); // 2MB
  unsigned short* fb   = (unsigned short*)(W + ((size_t)18 << 20)); // 4MB
  unsigned short* pb   = (unsigned short*)(W + ((size_t)22 << 20)); // 2MB

  prep_k<<<4096, 256, 0, stream>>>(id_x, frames, id_prev, x, fb, pb);

  static const int ssrc[10] = {0, 0, 0, 0, 1, 1, 2, 2, 1, 1};

  for (int i = 0; i < 10; i++) {
    const float* WqL = Wq + (size_t)i * 262144;
    const float* WkL = Wk + (size_t)i * 262144;
    const float* WvL = Wv + (size_t)i * 262144;
    const float* WoL = Wo + (size_t)i * 262144;
    const float* W1L = W1 + (size_t)i * 1048576;
    const float* W2L = W2 + (size_t)i * 1048576;

    if (i == 0)
      ln_bf<<<512, 256, 0, stream>>>(x, hb, l1g, l1b);

    const unsigned short* kvsrc; int Mkv;
    if (ssrc[i] == 0)      { kvsrc = fb; Mkv = 4096; }
    else if (ssrc[i] == 1) { kvsrc = xb; Mkv = 2048; }
    else                   { kvsrc = pb; Mkv = 2048; }
    gemm_qkv<<<256 + (Mkv / 64) * 16, 256, 0, stream>>>(
        hb, WqL, bq + i * 512, kvsrc, WkL, WvL, bk + i * 512, bv + i * 512, qbuf, kvb);

    if (ssrc[i] == 0)      attn_m<0, 1, 512><<<2048, 512, 0, stream>>>(qbuf, kvb, ybf);
    else if (ssrc[i] == 1) attn_m<1, 0, 256><<<2048, 512, 0, stream>>>(qbuf, kvb, ybf);
    else                   attn_m<0, 0, 256><<<2048, 512, 0, stream>>>(qbuf, kvb, ybf);

    // x = x + y @ Wo + bo
    gemm_bf<32, 0, 1, 0, 0><<<dim3(8, 64), 256, 0, stream>>>(ybf, WoL, bo + i * 512, x, x, 2048, 512, 512);
    // h = LN2(x) bf16
    ln_bf<<<512, 256, 0, stream>>>(x, hb, l2g + i * 512, l2b + i * 512);
    // m1 = gelu(h @ W1 + b1) bf16
    gemm_bf<128, 1, 0, 1, 0><<<dim3(32, 16), 256, 0, stream>>>(hb, W1L, b1 + i * 2048, m1b, nullptr, 2048, 2048, 512);
    // x = x + m1 @ W2 + b2
    gemm_bf<32, 0, 1, 0, 0><<<dim3(8, 64), 256, 0, stream>>>(m1b, W2L, b2 + i * 512, x, x, 2048, 512, 2048);

    if (i < 9)
      ln_chain<<<512, 256, 0, stream>>>(x, x, xb, lfg + i * 512, lfb + i * 512,
                                        l1g + (i + 1) * 512, l1b + (i + 1) * 512, hb);
    else
      ln_final<<<512, 256, 0, stream>>>(x, x, lfg + i * 512, lfb + i * 512);
  }
}

// Round 15
// 1143.984 us; speedup vs baseline: 1.1544x; 1.1544x over previous
//
#include <hip/hip_runtime.h>
#include <math.h>

#define CC 512
#define NH 8
#define HD 64
#define TT 256

typedef __attribute__((ext_vector_type(8))) short short8v;
typedef __attribute__((ext_vector_type(4))) float f32x4;

__device__ inline unsigned short bfc(float f) {  // fp32 -> bf16, RNE
  unsigned u = __float_as_uint(f);
  return (unsigned short)((u + 0x7fffu + ((u >> 16) & 1u)) >> 16);
}
__device__ inline float b2f(unsigned short s) {
  return __uint_as_float((unsigned)s << 16);
}
// async global->LDS, 16B per lane; l must be the wave-uniform base.
__device__ inline void gld16(const void* g, void* l) {
  __builtin_amdgcn_global_load_lds(
      (const __attribute__((address_space(1))) unsigned int*)g,
      (__attribute__((address_space(3))) unsigned int*)l, 16, 0, 0);
}

// ---------------- prep: x=id_x; fb=bf16(frames); pb=bf16(id_prev) ------------
__global__ __launch_bounds__(256) void prep_k(const float* __restrict__ id_x,
    const float* __restrict__ frames, const float* __restrict__ id_prev,
    float* __restrict__ x, unsigned short* __restrict__ fb,
    unsigned short* __restrict__ pb) {
  int i = blockIdx.x * 256 + threadIdx.x;
  if (i < 262144) {
    ((float4*)x)[i] = ((const float4*)id_x)[i];
  } else if (i < 786432) {
    int j = i - 262144;
    float4 f = ((const float4*)frames)[j];
    ushort4 o; o.x = bfc(f.x); o.y = bfc(f.y); o.z = bfc(f.z); o.w = bfc(f.w);
    ((ushort4*)fb)[j] = o;
  } else {
    int j = i - 786432;
    float4 f = ((const float4*)id_prev)[j];
    ushort4 o; o.x = bfc(f.x); o.y = bfc(f.y); o.z = bfc(f.z); o.w = bfc(f.w);
    ((ushort4*)pb)[j] = o;
  }
}

__global__ __launch_bounds__(256) void ln_final(const float* __restrict__ in,
    float* __restrict__ out, const float* __restrict__ g, const float* __restrict__ b) {
  int row = (blockIdx.x << 2) + (threadIdx.x >> 6), lane = threadIdx.x & 63;
  const float* r = in + (size_t)row * CC;
  float4 v0 = *(const float4*)(r + (lane << 2));
  float4 v1 = *(const float4*)(r + 256 + (lane << 2));
  float s = v0.x + v0.y + v0.z + v0.w + v1.x + v1.y + v1.z + v1.w;
  #pragma unroll
  for (int o = 32; o; o >>= 1) s += __shfl_xor(s, o);
  float mu = s * (1.0f / CC);
  float d0x = v0.x - mu, d0y = v0.y - mu, d0z = v0.z - mu, d0w = v0.w - mu;
  float d1x = v1.x - mu, d1y = v1.y - mu, d1z = v1.z - mu, d1w = v1.w - mu;
  float sq = d0x*d0x + d0y*d0y + d0z*d0z + d0w*d0w + d1x*d1x + d1y*d1y + d1z*d1z + d1w*d1w;
  #pragma unroll
  for (int o = 32; o; o >>= 1) sq += __shfl_xor(sq, o);
  float inv = rsqrtf(sq * (1.0f / CC) + 1e-5f);
  float4 g0 = *(const float4*)(g + (lane << 2)), g1 = *(const float4*)(g + 256 + (lane << 2));
  float4 b0 = *(const float4*)(b + (lane << 2)), b1 = *(const float4*)(b + 256 + (lane << 2));
  float4 o0, o1;
  o0.x = d0x*inv*g0.x + b0.x; o0.y = d0y*inv*g0.y + b0.y;
  o0.z = d0z*inv*g0.z + b0.z; o0.w = d0w*inv*g0.w + b0.w;
  o1.x = d1x*inv*g1.x + b1.x; o1.y = d1y*inv*g1.y + b1.y;
  o1.z = d1z*inv*g1.z + b1.z; o1.w = d1w*inv*g1.w + b1.w;
  *(float4*)(out + (size_t)row * CC + (lane << 2)) = o0;
  *(float4*)(out + (size_t)row * CC + 256 + (lane << 2)) = o1;
}

// LNf only: x fp32 + xb bf16 (LN1-of-next-layer now fused into GEMMs)
__global__ __launch_bounds__(256) void ln_chain(const float* __restrict__ in,
    float* __restrict__ xout, unsigned short* __restrict__ xb,
    const float* __restrict__ gf, const float* __restrict__ bf) {
  int row = (blockIdx.x << 2) + (threadIdx.x >> 6), lane = threadIdx.x & 63;
  const float* r = in + (size_t)row * CC;
  float4 v0 = *(const float4*)(r + (lane << 2));
  float4 v1 = *(const float4*)(r + 256 + (lane << 2));
  float s = v0.x + v0.y + v0.z + v0.w + v1.x + v1.y + v1.z + v1.w;
  #pragma unroll
  for (int o = 32; o; o >>= 1) s += __shfl_xor(s, o);
  float mu = s * (1.0f / CC);
  float d0x = v0.x - mu, d0y = v0.y - mu, d0z = v0.z - mu, d0w = v0.w - mu;
  float d1x = v1.x - mu, d1y = v1.y - mu, d1z = v1.z - mu, d1w = v1.w - mu;
  float sq = d0x*d0x + d0y*d0y + d0z*d0z + d0w*d0w + d1x*d1x + d1y*d1y + d1z*d1z + d1w*d1w;
  #pragma unroll
  for (int o = 32; o; o >>= 1) sq += __shfl_xor(sq, o);
  float inv = rsqrtf(sq * (1.0f / CC) + 1e-5f);
  float4 g0 = *(const float4*)(gf + (lane << 2)), g1v = *(const float4*)(gf + 256 + (lane << 2));
  float4 b0 = *(const float4*)(bf + (lane << 2)), b1v = *(const float4*)(bf + 256 + (lane << 2));
  float4 x0, x1;
  x0.x = d0x*inv*g0.x + b0.x; x0.y = d0y*inv*g0.y + b0.y;
  x0.z = d0z*inv*g0.z + b0.z; x0.w = d0w*inv*g0.w + b0.w;
  x1.x = d1x*inv*g1v.x + b1v.x; x1.y = d1y*inv*g1v.y + b1v.y;
  x1.z = d1z*inv*g1v.z + b1v.z; x1.w = d1w*inv*g1v.w + b1v.w;
  *(float4*)(xout + (size_t)row * CC + (lane << 2)) = x0;
  *(float4*)(xout + (size_t)row * CC + 256 + (lane << 2)) = x1;
  ushort4 xb0, xb1;
  xb0.x = bfc(x0.x); xb0.y = bfc(x0.y); xb0.z = bfc(x0.z); xb0.w = bfc(x0.w);
  xb1.x = bfc(x1.x); xb1.y = bfc(x1.y); xb1.z = bfc(x1.z); xb1.w = bfc(x1.w);
  *(ushort4*)(xb + (size_t)row * CC + (lane << 2)) = xb0;
  *(ushort4*)(xb + (size_t)row * CC + 256 + (lane << 2)) = xb1;
}

// ---------------- weight transpose+convert (32x32 tiles, proven fastest) -----
__global__ __launch_bounds__(256) void transpose_w(
    const float* __restrict__ Wq, const float* __restrict__ Wk,
    const float* __restrict__ Wv, const float* __restrict__ Wo,
    const float* __restrict__ W1, const float* __restrict__ W2,
    int layer_base, unsigned short* __restrict__ wT) {
  int lz = blockIdx.x / 3072;
  int layer = layer_base + lz;
  int bid = blockIdx.x - lz * 3072;
  unsigned short* wTl = wT + (size_t)lz * 3145728;
  const float* src; unsigned short* dst; int R, Cn, tile, lg;
  if (bid < 1024) {
    int seg = bid >> 8; tile = bid & 255; R = 512; Cn = 512; lg = 4;
    const float* s4[4] = {Wq, Wk, Wv, Wo};
    src = s4[seg] + (size_t)layer * 262144;
    dst = wTl + (size_t)seg * 262144;
  } else if (bid < 2048) {
    tile = bid - 1024; R = 512; Cn = 2048; lg = 6;
    src = W1 + (size_t)layer * 1048576; dst = wTl + 1048576;
  } else {
    tile = bid - 2048; R = 2048; Cn = 512; lg = 4;
    src = W2 + (size_t)layer * 1048576; dst = wTl + 2097152;
  }
  int trb = tile >> lg, tcb = tile & ((1 << lg) - 1);
  __shared__ float tl[32][33];
  int t = threadIdx.x;
  int r = t >> 3, c4 = (t & 7) << 2;
  const float* sp = src + (size_t)(trb * 32 + r) * Cn + tcb * 32 + c4;
  float4 fv = *(const float4*)sp;
  tl[r][c4] = fv.x; tl[r][c4 + 1] = fv.y; tl[r][c4 + 2] = fv.z; tl[r][c4 + 3] = fv.w;
  __syncthreads();
  unsigned short* dp = dst + (size_t)(tcb * 32 + r) * R + trb * 32 + c4;
  ushort4 ov;
  ov.x = bfc(tl[c4][r]); ov.y = bfc(tl[c4 + 1][r]);
  ov.z = bfc(tl[c4 + 2][r]); ov.w = bfc(tl[c4 + 3][r]);
  *(ushort4*)dp = ov;
}

// ---------------- bf16 MFMA GEMM, dbuf gld16 (o-proj / mlp2) -----------------
template<int BM, int GELU, int RES, int OUTBF>
__global__ __launch_bounds__(256) void gemm_bf(
    const unsigned short* __restrict__ A, const unsigned short* __restrict__ WT,
    const float* __restrict__ bias,
    void* __restrict__ outp, const float* __restrict__ res, int M, int N, int K) {
  __shared__ __align__(16) unsigned short As[2][BM * 64];
  __shared__ __align__(16) unsigned short Bs[2][64 * 64];
  const int tid = threadIdx.x, lane = tid & 63, wid = tid >> 6;
  const int bm = blockIdx.y * BM, bn = blockIdx.x << 6;
  const int wm = (wid >> 1) * (BM / 2), wn = (wid & 1) << 5;
  constexpr int MF = BM / 32;
  f32x4 acc[MF][2] = {};
  const int fr = lane & 15, fq = lane >> 4;
  const int srow_a = tid >> 3, sgc = tid & 7;

  auto stage = [&](int buf, int k0) {
    #pragma unroll
    for (int i = 0; i < BM / 32; i++) {
      int row = srow_a + (i << 5);
      int gcs = sgc ^ (row & 7);
      gld16(A + (size_t)(bm + row) * K + k0 + (gcs << 3),
            (char*)As[buf] + (i << 12) + (wid << 10));
    }
    #pragma unroll
    for (int i = 0; i < 2; i++) {
      int row = srow_a + (i << 5);
      int gcs = sgc ^ (row & 7);
      gld16(WT + (size_t)(bn + row) * K + k0 + (gcs << 3),
            (char*)Bs[buf] + (i << 12) + (wid << 10));
    }
  };

  stage(0, 0);
  __syncthreads();
  int cur = 0;
  for (int k0 = 0; k0 < K; k0 += 64) {
    if (k0 + 64 < K) stage(cur ^ 1, k0 + 64);
    short8v af[MF][2], bf2[2][2];
    #pragma unroll
    for (int mf = 0; mf < MF; mf++)
      #pragma unroll
      for (int ks = 0; ks < 2; ks++) {
        int r = wm + mf * 16 + fr;
        int c = (ks << 2) + fq;
        af[mf][ks] = *(const short8v*)((const char*)As[cur] + ((((r << 7) + (c << 4))) ^ ((r & 7) << 4)));
      }
    #pragma unroll
    for (int nf = 0; nf < 2; nf++)
      #pragma unroll
      for (int ks = 0; ks < 2; ks++) {
        int r = wn + nf * 16 + fr;
        int c = (ks << 2) + fq;
        bf2[nf][ks] = *(const short8v*)((const char*)Bs[cur] + ((((r << 7) + (c << 4))) ^ ((r & 7) << 4)));
      }
    #pragma unroll
    for (int mf = 0; mf < MF; mf++)
      #pragma unroll
      for (int nf = 0; nf < 2; nf++) {
        acc[mf][nf] = __builtin_amdgcn_mfma_f32_16x16x32_bf16(af[mf][0], bf2[nf][0], acc[mf][nf], 0, 0, 0);
        acc[mf][nf] = __builtin_amdgcn_mfma_f32_16x16x32_bf16(af[mf][1], bf2[nf][1], acc[mf][nf], 0, 0, 0);
      }
    __syncthreads();
    cur ^= 1;
  }
  #pragma unroll
  for (int mf = 0; mf < MF; mf++)
    #pragma unroll
    for (int nf = 0; nf < 2; nf++) {
      int col = bn + wn + nf * 16 + fr;
      float bia = bias[col];
      #pragma unroll
      for (int rr = 0; rr < 4; rr++) {
        int row = bm + wm + mf * 16 + fq * 4 + rr;
        float vv = acc[mf][nf][rr] + bia;
        if (GELU) vv = 0.5f * vv * (1.0f + erff(vv * 0.70710678118654752f));
        if (RES)  vv += res[(size_t)row * N + col];
        if (OUTBF) ((unsigned short*)outp)[(size_t)row * N + col] = bfc(vv);
        else       ((float*)outp)[(size_t)row * N + col] = vv;
      }
    }
}

// ---------------- GEMM with fused LayerNorm on A (mlp1) ----------------------
// A = LN(xf rows) computed in-block: 8-lane-group stats, fp32 load -> LN ->
// bf16 ds_write (row-major, swizzled). K=512. out = act(A@W + bias).
template<int GELU, int OUTBF, int QSC>
__global__ __launch_bounds__(256) void gemm_ln(
    const float* __restrict__ xf, const float* __restrict__ lng,
    const float* __restrict__ lnb, const unsigned short* __restrict__ WT,
    const float* __restrict__ bias, void* __restrict__ outp, int N) {
  __shared__ __align__(16) unsigned short As[2][64 * 64];
  __shared__ __align__(16) unsigned short Bs[2][64 * 64];
  __shared__ float gls[512], bls[512], muv[64], invv[64];
  const int tid = threadIdx.x, lane = tid & 63, wid = tid >> 6;
  const int bm = blockIdx.y << 6, bn = blockIdx.x << 6;
  const int wm = (wid >> 1) << 5, wn = (wid & 1) << 5;
  f32x4 acc[2][2] = {};
  const int fr = lane & 15, fq = lane >> 4;
  const int srow_b = tid >> 3, sgc = tid & 7;
  {  // LN stats: wave handles 16 rows, 8 rows in parallel per pass
    int sl = lane & 7;
    #pragma unroll
    for (int p = 0; p < 2; p++) {
      int row = (wid << 4) + (p << 3) + (lane >> 3);
      const float* rp = xf + (size_t)(bm + row) * 512;
      float s = 0.f, sq = 0.f;
      #pragma unroll
      for (int i = 0; i < 16; i++) {
        float4 v = *(const float4*)(rp + (i << 5) + (sl << 2));
        s  += v.x + v.y + v.z + v.w;
        sq += v.x*v.x + v.y*v.y + v.z*v.z + v.w*v.w;
      }
      s  += __shfl_xor(s, 1);  s  += __shfl_xor(s, 2);  s  += __shfl_xor(s, 4);
      sq += __shfl_xor(sq, 1); sq += __shfl_xor(sq, 2); sq += __shfl_xor(sq, 4);
      if (sl == 0) {
        float mu = s * (1.f / 512.f);
        muv[row] = mu;
        invv[row] = rsqrtf(sq * (1.f / 512.f) - mu * mu + 1e-5f);
      }
    }
    if (tid < 128) ((float4*)gls)[tid] = ((const float4*)lng)[tid];
    else           ((float4*)bls)[tid - 128] = ((const float4*)lnb)[tid - 128];
  }
  __syncthreads();
  const int arow = tid >> 2, acg = tid & 3;
  const float muR = muv[arow], ivR = invv[arow];
  float4 areg[4];
  auto loadA = [&](int k0) {
    #pragma unroll
    for (int j = 0; j < 4; j++)
      areg[j] = *(const float4*)(xf + (size_t)(bm + arow) * 512 + k0 + (acg << 4) + (j << 2));
  };
  auto writeA = [&](int buf, int k0) {
    #pragma unroll
    for (int j = 0; j < 4; j++) {
      int k = (acg << 4) + (j << 2);
      float4 g4 = *(const float4*)(gls + k0 + k);
      float4 b4 = *(const float4*)(bls + k0 + k);
      ushort4 o;
      o.x = bfc((areg[j].x - muR) * ivR * g4.x + b4.x);
      o.y = bfc((areg[j].y - muR) * ivR * g4.y + b4.y);
      o.z = bfc((areg[j].z - muR) * ivR * g4.z + b4.z);
      o.w = bfc((areg[j].w - muR) * ivR * g4.w + b4.w);
      *(ushort4*)((char*)As[buf] + (((arow << 7) + (k << 1)) ^ ((arow & 7) << 4))) = o;
    }
  };
  auto stageB = [&](int buf, int k0) {
    #pragma unroll
    for (int i = 0; i < 2; i++) {
      int row = srow_b + (i << 5);
      int gcs = sgc ^ (row & 7);
      gld16(WT + (size_t)(bn + row) * 512 + k0 + (gcs << 3),
            (char*)Bs[buf] + (i << 12) + (wid << 10));
    }
  };
  loadA(0); stageB(0, 0); writeA(0, 0);
  __syncthreads();
  int cur = 0;
  for (int k0 = 0; k0 < 512; k0 += 64) {
    bool more = (k0 + 64 < 512);
    if (more) { loadA(k0 + 64); stageB(cur ^ 1, k0 + 64); }
    short8v af[2][2], bf2[2][2];
    #pragma unroll
    for (int mf = 0; mf < 2; mf++)
      #pragma unroll
      for (int ks = 0; ks < 2; ks++) {
        int r = wm + mf * 16 + fr;
        int c = (ks << 2) + fq;
        af[mf][ks] = *(const short8v*)((const char*)As[cur] + ((((r << 7) + (c << 4))) ^ ((r & 7) << 4)));
        int r2 = wn + mf * 16 + fr;
        bf2[mf][ks] = *(const short8v*)((const char*)Bs[cur] + ((((r2 << 7) + (c << 4))) ^ ((r2 & 7) << 4)));
      }
    #pragma unroll
    for (int mf = 0; mf < 2; mf++)
      #pragma unroll
      for (int nf = 0; nf < 2; nf++) {
        acc[mf][nf] = __builtin_amdgcn_mfma_f32_16x16x32_bf16(af[mf][0], bf2[nf][0], acc[mf][nf], 0, 0, 0);
        acc[mf][nf] = __builtin_amdgcn_mfma_f32_16x16x32_bf16(af[mf][1], bf2[nf][1], acc[mf][nf], 0, 0, 0);
      }
    if (more) writeA(cur ^ 1, k0 + 64);
    __syncthreads();
    cur ^= 1;
  }
  #pragma unroll
  for (int mf = 0; mf < 2; mf++)
    #pragma unroll
    for (int nf = 0; nf < 2; nf++) {
      int col = bn + wn + nf * 16 + fr;
      float bia = bias[col];
      #pragma unroll
      for (int rr = 0; rr < 4; rr++) {
        int row = bm + wm + mf * 16 + fq * 4 + rr;
        float vv = acc[mf][nf][rr] + bia;
        if (GELU) vv = 0.5f * vv * (1.0f + erff(vv * 0.70710678118654752f));
        if (QSC)  vv *= 0.125f;
        if (OUTBF) ((unsigned short*)outp)[(size_t)row * N + col] = bfc(vv);
        else       ((float*)outp)[(size_t)row * N + col] = vv;
      }
    }
}

// ---------------- merged q-proj (fused LN1) + kv-proj ------------------------
// blocks [0,256): q = (LN1(x)@WqT + bq)*0.125 -> qbuf
// blocks [256,..): kv = kvA@WkvT + [bk|bv] -> kvb [Mkv][1024]
__global__ __launch_bounds__(256) void gemm_qkv(
    const float* __restrict__ xf, const float* __restrict__ l1g,
    const float* __restrict__ l1b, const unsigned short* __restrict__ wqT,
    const float* __restrict__ bq,
    const unsigned short* __restrict__ kvA, const unsigned short* __restrict__ wkvT,
    const float* __restrict__ bk, const float* __restrict__ bv,
    unsigned short* __restrict__ qout, unsigned short* __restrict__ kvout) {
  __shared__ __align__(16) unsigned short As[2][64 * 64];
  __shared__ __align__(16) unsigned short Bs[2][64 * 64];
  __shared__ float gls[512], bls[512], muv[64], invv[64];
  const int tid = threadIdx.x, lane = tid & 63, wid = tid >> 6;
  const int bid = blockIdx.x;
  const bool isq = bid < 256;
  const int wm = (wid >> 1) << 5, wn = (wid & 1) << 5;
  f32x4 acc[2][2] = {};
  const int fr = lane & 15, fq = lane >> 4;
  const int srow = tid >> 3, sgc = tid & 7;

  if (isq) {
    const int bm = (bid >> 3) << 6, bn = (bid & 7) << 6;
    {  // LN1 stats
      int sl = lane & 7;
      #pragma unroll
      for (int p = 0; p < 2; p++) {
        int row = (wid << 4) + (p << 3) + (lane >> 3);
        const float* rp = xf + (size_t)(bm + row) * 512;
        float s = 0.f, sq = 0.f;
        #pragma unroll
        for (int i = 0; i < 16; i++) {
          float4 v = *(const float4*)(rp + (i << 5) + (sl << 2));
          s  += v.x + v.y + v.z + v.w;
          sq += v.x*v.x + v.y*v.y + v.z*v.z + v.w*v.w;
        }
        s  += __shfl_xor(s, 1);  s  += __shfl_xor(s, 2);  s  += __shfl_xor(s, 4);
        sq += __shfl_xor(sq, 1); sq += __shfl_xor(sq, 2); sq += __shfl_xor(sq, 4);
        if (sl == 0) {
          float mu = s * (1.f / 512.f);
          muv[row] = mu;
          invv[row] = rsqrtf(sq * (1.f / 512.f) - mu * mu + 1e-5f);
        }
      }
      if (tid < 128) ((float4*)gls)[tid] = ((const float4*)l1g)[tid];
      else           ((float4*)bls)[tid - 128] = ((const float4*)l1b)[tid - 128];
    }
    __syncthreads();
    const int arow = tid >> 2, acg = tid & 3;
    const float muR = muv[arow], ivR = invv[arow];
    float4 areg[4];
    auto loadA = [&](int k0) {
      #pragma unroll
      for (int j = 0; j < 4; j++)
        areg[j] = *(const float4*)(xf + (size_t)(bm + arow) * 512 + k0 + (acg << 4) + (j << 2));
    };
    auto writeA = [&](int buf, int k0) {
      #pragma unroll
      for (int j = 0; j < 4; j++) {
        int k = (acg << 4) + (j << 2);
        float4 g4 = *(const float4*)(gls + k0 + k);
        float4 b4 = *(const float4*)(bls + k0 + k);
        ushort4 o;
        o.x = bfc((areg[j].x - muR) * ivR * g4.x + b4.x);
        o.y = bfc((areg[j].y - muR) * ivR * g4.y + b4.y);
        o.z = bfc((areg[j].z - muR) * ivR * g4.z + b4.z);
        o.w = bfc((areg[j].w - muR) * ivR * g4.w + b4.w);
        *(ushort4*)((char*)As[buf] + (((arow << 7) + (k << 1)) ^ ((arow & 7) << 4))) = o;
      }
    };
    auto stageB = [&](int buf, int k0) {
      #pragma unroll
      for (int i = 0; i < 2; i++) {
        int row = srow + (i << 5);
        int gcs = sgc ^ (row & 7);
        gld16(wqT + (size_t)(bn + row) * 512 + k0 + (gcs << 3),
              (char*)Bs[buf] + (i << 12) + (wid << 10));
      }
    };
    loadA(0); stageB(0, 0); writeA(0, 0);
    __syncthreads();
    int cur = 0;
    for (int k0 = 0; k0 < 512; k0 += 64) {
      bool more = (k0 + 64 < 512);
      if (more) { loadA(k0 + 64); stageB(cur ^ 1, k0 + 64); }
      short8v af[2][2], bf2[2][2];
      #pragma unroll
      for (int mf = 0; mf < 2; mf++)
        #pragma unroll
        for (int ks = 0; ks < 2; ks++) {
          int r = wm + mf * 16 + fr;
          int c = (ks << 2) + fq;
          af[mf][ks] = *(const short8v*)((const char*)As[cur] + ((((r << 7) + (c << 4))) ^ ((r & 7) << 4)));
          int r2 = wn + mf * 16 + fr;
          bf2[mf][ks] = *(const short8v*)((const char*)Bs[cur] + ((((r2 << 7) + (c << 4))) ^ ((r2 & 7) << 4)));
        }
      #pragma unroll
      for (int mf = 0; mf < 2; mf++)
        #pragma unroll
        for (int nf = 0; nf < 2; nf++) {
          acc[mf][nf] = __builtin_amdgcn_mfma_f32_16x16x32_bf16(af[mf][0], bf2[nf][0], acc[mf][nf], 0, 0, 0);
          acc[mf][nf] = __builtin_amdgcn_mfma_f32_16x16x32_bf16(af[mf][1], bf2[nf][1], acc[mf][nf], 0, 0, 0);
        }
      if (more) writeA(cur ^ 1, k0 + 64);
      __syncthreads();
      cur ^= 1;
    }
    #pragma unroll
    for (int mf = 0; mf < 2; mf++)
      #pragma unroll
      for (int nf = 0; nf < 2; nf++) {
        int col = bn + wn + nf * 16 + fr;
        float bia = bq[col];
        #pragma unroll
        for (int rr = 0; rr < 4; rr++) {
          int row = bm + wm + mf * 16 + fq * 4 + rr;
          float vv = (acc[mf][nf][rr] + bia) * 0.125f;
          qout[(size_t)row * 512 + col] = bfc(vv);
        }
      }
  } else {
    const int t = bid - 256;
    const int bm = (t >> 4) << 6, bn = (t & 15) << 6;
    auto stage = [&](int buf, int k0) {
      #pragma unroll
      for (int i = 0; i < 2; i++) {
        int row = srow + (i << 5);
        int gcs = sgc ^ (row & 7);
        gld16(kvA + (size_t)(bm + row) * 512 + k0 + (gcs << 3),
              (char*)As[buf] + (i << 12) + (wid << 10));
        gld16(wkvT + (size_t)(bn + row) * 512 + k0 + (gcs << 3),
              (char*)Bs[buf] + (i << 12) + (wid << 10));
      }
    };
    stage(0, 0);
    __syncthreads();
    int cur = 0;
    for (int k0 = 0; k0 < 512; k0 += 64) {
      if (k0 + 64 < 512) stage(cur ^ 1, k0 + 64);
      short8v af[2][2], bf2[2][2];
      #pragma unroll
      for (int mf = 0; mf < 2; mf++)
        #pragma unroll
        for (int ks = 0; ks < 2; ks++) {
          int r = wm + mf * 16 + fr;
          int c = (ks << 2) + fq;
          af[mf][ks] = *(const short8v*)((const char*)As[cur] + ((((r << 7) + (c << 4))) ^ ((r & 7) << 4)));
          int r2 = wn + mf * 16 + fr;
          bf2[mf][ks] = *(const short8v*)((const char*)Bs[cur] + ((((r2 << 7) + (c << 4))) ^ ((r2 & 7) << 4)));
        }
      #pragma unroll
      for (int mf = 0; mf < 2; mf++)
        #pragma unroll
        for (int nf = 0; nf < 2; nf++) {
          acc[mf][nf] = __builtin_amdgcn_mfma_f32_16x16x32_bf16(af[mf][0], bf2[nf][0], acc[mf][nf], 0, 0, 0);
          acc[mf][nf] = __builtin_amdgcn_mfma_f32_16x16x32_bf16(af[mf][1], bf2[nf][1], acc[mf][nf], 0, 0, 0);
        }
      __syncthreads();
      cur ^= 1;
    }
    #pragma unroll
    for (int mf = 0; mf < 2; mf++)
      #pragma unroll
      for (int nf = 0; nf < 2; nf++) {
        int col = bn + wn + nf * 16 + fr;
        float bia = (col >= 512) ? bv[col - 512] : bk[col];
        #pragma unroll
        for (int rr = 0; rr < 4; rr++) {
          int row = bm + wm + mf * 16 + fq * 4 + rr;
          kvout[(size_t)row * 1024 + col] = bfc(acc[mf][nf][rr] + bia);
        }
      }
  }
}

// ---------------- MFMA attention: 8 q-rows/block, double-buffered K tiles ----
template<int CAUSAL, int TOPK, int TSK>
__global__ __launch_bounds__(512, 4) void attn_m(
    const unsigned short* __restrict__ qb, const unsigned short* __restrict__ kv,
    unsigned short* __restrict__ yb) {
  constexpr int NT = TSK / 64;
  constexpr int NKC = TSK / 128;
  constexpr int SST = TSK + 8;
  constexpr int SBYTES = 8 * SST * 4;
  __shared__ __align__(16) char sm[SBYTES + 32768 + 2048];
  float* S = (float*)sm;
  char* KsB = sm + SBYTES;
  char* Qs  = sm + SBYTES + 32768;
  float* swt = (float*)KsB;
  unsigned short* kidx = (unsigned short*)(KsB + 4096);
  int tid = threadIdx.x, lane = tid & 63, wid = tid >> 6;
  int bid = blockIdx.x;
  int swz = ((bid & 7) << 8) | (bid >> 3);
  int b = swz >> 8, h = (swz >> 5) & 7, q0 = (swz & 31) << 3;
  if (tid < 64) {
    int row = tid >> 3, sp = tid & 7;
    gld16(qb + (size_t)((b << 8) + q0 + row) * CC + (h << 6) + ((sp ^ (row & 7)) << 3),
          Qs);
  } else if (tid < 128) {
    short8v z = {0, 0, 0, 0, 0, 0, 0, 0};
    *(short8v*)(Qs + (tid << 4)) = z;
  }
  const unsigned short* kgb = kv + (size_t)b * TSK * 1024 + (h << 6);
  int nte = NKC;
  if (CAUSAL) { int ub = (q0 + 8 + 127) >> 7; nte = ub < NKC ? ub : NKC; }
  auto stageK = [&](int buf, int t) {
    #pragma unroll
    for (int j = 0; j < 2; j++) {
      int s = (wid << 7) + (j << 6) + lane;
      int row = s >> 3, sp = s & 7;
      gld16(kgb + (size_t)((t << 7) + row) * 1024 + ((sp ^ (row & 7)) << 3),
            KsB + (buf << 14) + (wid << 11) + (j << 10));
    }
  };
  stageK(0, 0);
  __syncthreads();
  short8v aF[2];
  {
    int r = lane & 15, kq2 = lane >> 4;
    #pragma unroll
    for (int kc2 = 0; kc2 < 2; kc2++)
      aF[kc2] = *(const short8v*)(Qs +
                 (((r << 7) + (kc2 << 6) + (kq2 << 4)) ^ ((r & 7) << 4)));
  }
  int cur = 0;
  for (int t = 0; t < nte; t++) {
    if (t + 1 < nte) stageK(cur ^ 1, t + 1);
    int kq2 = lane >> 4;
    f32x4 acc = {};
    int key16 = (wid << 4) + (lane & 15);
    #pragma unroll
    for (int kc2 = 0; kc2 < 2; kc2++) {
      short8v bF = *(const short8v*)(KsB + (cur << 14) +
                    (((key16 << 7) + (kc2 << 6) + (kq2 << 4)) ^ ((key16 & 7) << 4)));
      acc = __builtin_amdgcn_mfma_f32_16x16x32_bf16(aF[kc2], bF, acc, 0, 0, 0);
    }
    if (kq2 < 2) {
      int col = (t << 7) + key16;
      #pragma unroll
      for (int r = 0; r < 4; r++)
        S[(kq2 * 4 + r) * SST + col] = acc[r];
    }
    __syncthreads();
    cur ^= 1;
  }
  int row = wid;
  int qi = q0 + row;
  int jmax = CAUSAL ? (qi + 1) : TSK;
  const unsigned short* vgb = kv + (size_t)b * TSK * 1024 + 512 + (h << 6) + lane;
  float sc[NT];
  float lmax = -3.0e38f;
  #pragma unroll
  for (int tt = 0; tt < NT; tt++) {
    int key = lane + (tt << 6);
    float v = (!CAUSAL || key < jmax) ? S[row * SST + key] : -3.0e38f;
    sc[tt] = v;
    lmax = fmaxf(lmax, v);
  }
  float mx = lmax;
  #pragma unroll
  for (int o = 32; o; o >>= 1) mx = fmaxf(mx, __shfl_xor(mx, o));
  float oacc = 0.f;
  if (TOPK) {
    unsigned key[NT];
    #pragma unroll
    for (int tt = 0; tt < NT; tt++) {
      unsigned u = __float_as_uint(sc[tt]);
      key[tt] = (u & 0x80000000u) ? ~u : (u | 0x80000000u);
    }
    unsigned prefix = 0u;
    for (int bit = 31; bit >= 0; bit--) {
      unsigned cand = prefix | (1u << bit);
      int cnt = 0;
      #pragma unroll
      for (int tt = 0; tt < NT; tt++)
        cnt += __popcll(__ballot(key[tt] >= cand));
      if (cnt >= 64) {
        prefix = cand;
        if (cnt == 64) break;
      }
    }
    float wvv[NT];
    float psum = 0.f;
    int basec = 0;
    #pragma unroll
    for (int tt = 0; tt < NT; tt++) {
      bool keep = key[tt] >= prefix;
      float wv = keep ? exp2f((sc[tt] - mx) * 1.4426950408889634f) : 0.f;
      wvv[tt] = wv;
      psum += wv;
      unsigned long long mask = __ballot(keep);
      if (keep) {
        int pos = basec + (int)__popcll(mask & ((1ull << lane) - 1ull));
        if (pos < 128) {
          kidx[(row << 7) + pos] = (unsigned short)(lane + (tt << 6));
          swt[(row << 7) + pos] = wv;
        }
      }
      basec += (int)__popcll(mask);
    }
    #pragma unroll
    for (int o = 32; o; o >>= 1) psum += __shfl_xor(psum, o);
    float inv = 1.0f / psum;
    int nk = basec;
    if (nk <= 128) {
      float a0 = 0.f, a1 = 0.f, a2 = 0.f, a3 = 0.f;
      int i = 0;
      for (; i + 3 < nk; i += 4) {
        a0 += swt[(row << 7) + i]     * b2f(vgb[(size_t)kidx[(row << 7) + i] * 1024]);
        a1 += swt[(row << 7) + i + 1] * b2f(vgb[(size_t)kidx[(row << 7) + i + 1] * 1024]);
        a2 += swt[(row << 7) + i + 2] * b2f(vgb[(size_t)kidx[(row << 7) + i + 2] * 1024]);
        a3 += swt[(row << 7) + i + 3] * b2f(vgb[(size_t)kidx[(row << 7) + i + 3] * 1024]);
      }
      for (; i < nk; i++) a0 += swt[(row << 7) + i] * b2f(vgb[(size_t)kidx[(row << 7) + i] * 1024]);
      oacc = (a0 + a1 + a2 + a3) * inv;
    } else {
      #pragma unroll
      for (int tt = 0; tt < NT; tt++)
        S[row * SST + lane + (tt << 6)] = wvv[tt];
      float a0 = 0.f, a1 = 0.f;
      for (int j = 0; j + 1 < TSK; j += 2) {
        a0 += S[row * SST + j]     * b2f(vgb[(size_t)j * 1024]);
        a1 += S[row * SST + j + 1] * b2f(vgb[(size_t)(j + 1) * 1024]);
      }
      oacc = (a0 + a1) * inv;
    }
  } else {
    float psum = 0.f;
    #pragma unroll
    for (int tt = 0; tt < NT; tt++) {
      int keyj = lane + (tt << 6);
      float wv = (keyj < jmax) ? exp2f((sc[tt] - mx) * 1.4426950408889634f) : 0.f;
      S[row * SST + keyj] = wv;
      psum += wv;
    }
    #pragma unroll
    for (int o = 32; o; o >>= 1) psum += __shfl_xor(psum, o);
    float inv = 1.0f / psum;
    float a0 = 0.f, a1 = 0.f, a2 = 0.f, a3 = 0.f;
    int j = 0;
    for (; j + 3 < jmax; j += 4) {
      a0 += S[row * SST + j]     * b2f(vgb[(size_t)j * 1024]);
      a1 += S[row * SST + j + 1] * b2f(vgb[(size_t)(j + 1) * 1024]);
      a2 += S[row * SST + j + 2] * b2f(vgb[(size_t)(j + 2) * 1024]);
      a3 += S[row * SST + j + 3] * b2f(vgb[(size_t)(j + 3) * 1024]);
    }
    for (; j < jmax; j++) a0 += S[row * SST + j] * b2f(vgb[(size_t)j * 1024]);
    oacc = (a0 + a1 + a2 + a3) * inv;
  }
  yb[(size_t)((b << 8) + qi) * CC + (h << 6) + lane] = bfc(oacc);
}

extern "C" void kernel_launch(void* const* d_in, const int* in_sizes, int n_in,
                              void* d_out, int out_size, void* d_ws, size_t ws_size,
                              hipStream_t stream) {
  const float* id_x    = (const float*)d_in[0];
  const float* id_prev = (const float*)d_in[1];
  const float* frames  = (const float*)d_in[2];
  const float* Wq = (const float*)d_in[3];  const float* bq = (const float*)d_in[4];
  const float* Wk = (const float*)d_in[5];  const float* bk = (const float*)d_in[6];
  const float* Wv = (const float*)d_in[7];  const float* bv = (const float*)d_in[8];
  const float* Wo = (const float*)d_in[9];  const float* bo = (const float*)d_in[10];
  const float* W1 = (const float*)d_in[11]; const float* b1 = (const float*)d_in[12];
  const float* W2 = (const float*)d_in[13]; const float* b2 = (const float*)d_in[14];
  const float* l1g = (const float*)d_in[15]; const float* l1b = (const float*)d_in[16];
  const float* l2g = (const float*)d_in[17]; const float* l2b = (const float*)d_in[18];
  const float* lfg = (const float*)d_in[19]; const float* lfb = (const float*)d_in[20];

  float* x = (float*)d_out;
  char* W  = (char*)d_ws;
  unsigned short* qbuf = (unsigned short*)W;                        // 2MB bf16 q (pre-scaled)
  unsigned short* kvb  = (unsigned short*)(W + ((size_t)4  << 20)); // 8MB packed K|V
  unsigned short* m1b  = (unsigned short*)(W + ((size_t)4  << 20)); // 8MB, alias kv
  unsigned short* ybf  = (unsigned short*)(W + ((size_t)14 << 20)); // 2MB
  unsigned short* xb   = (unsigned short*)(W + ((size_t)16 << 20)); // 2MB
  unsigned short* fb   = (unsigned short*)(W + ((size_t)18 << 20)); // 4MB
  unsigned short* pb   = (unsigned short*)(W + ((size_t)22 << 20)); // 2MB
  unsigned short* wT   = (unsigned short*)(W + ((size_t)24 << 20)); // 6MB or 60MB

  const bool allw = ws_size >= (((size_t)24 << 20) + (size_t)10 * 3145728 * 2);

  prep_k<<<4096, 256, 0, stream>>>(id_x, frames, id_prev, x, fb, pb);
  if (allw)
    transpose_w<<<30720, 256, 0, stream>>>(Wq, Wk, Wv, Wo, W1, W2, 0, wT);

  static const int ssrc[10] = {0, 0, 0, 0, 1, 1, 2, 2, 1, 1};

  for (int i = 0; i < 10; i++) {
    if (!allw)
      transpose_w<<<3072, 256, 0, stream>>>(Wq, Wk, Wv, Wo, W1, W2, i, wT);
    unsigned short* wTl = wT + (allw ? (size_t)i * 3145728 : 0);
    unsigned short* wqT = wTl;
    unsigned short* wkvT = wTl + 262144;   // [1024][512]: K rows then V rows
    unsigned short* woT = wTl + 786432;
    unsigned short* w1T = wTl + 1048576;
    unsigned short* w2T = wTl + 2097152;

    const unsigned short* kvsrc; int Mkv;
    if (ssrc[i] == 0)      { kvsrc = fb; Mkv = 4096; }
    else if (ssrc[i] == 1) { kvsrc = xb; Mkv = 2048; }
    else                   { kvsrc = pb; Mkv = 2048; }
    // merged q-proj (fused LN1) + kv-proj
    gemm_qkv<<<256 + (Mkv / 64) * 16, 256, 0, stream>>>(
        x, l1g + i * 512, l1b + i * 512, wqT, bq + i * 512,
        kvsrc, wkvT, bk + i * 512, bv + i * 512, qbuf, kvb);

    if (ssrc[i] == 0)      attn_m<0, 1, 512><<<2048, 512, 0, stream>>>(qbuf, kvb, ybf);
    else if (ssrc[i] == 1) attn_m<1, 0, 256><<<2048, 512, 0, stream>>>(qbuf, kvb, ybf);
    else                   attn_m<0, 0, 256><<<2048, 512, 0, stream>>>(qbuf, kvb, ybf);

    // x = x + y @ Wo + bo
    gemm_bf<32, 0, 1, 0><<<dim3(8, 64), 256, 0, stream>>>(ybf, woT, bo + i * 512, x, x, 2048, 512, 512);
    // m1 = gelu(LN2(x) @ W1 + b1) bf16  (LN2 fused)
    gemm_ln<1, 1, 0><<<dim3(32, 32), 256, 0, stream>>>(x, l2g + i * 512, l2b + i * 512,
                                                       w1T, b1 + i * 2048, m1b, 2048);
    // x = x + m1 @ W2 + b2
    gemm_bf<32, 0, 1, 0><<<dim3(8, 64), 256, 0, stream>>>(m1b, w2T, b2 + i * 512, x, x, 2048, 512, 2048);

    if (i < 9)
      ln_chain<<<512, 256, 0, stream>>>(x, x, xb, lfg + i * 512, lfb + i * 512);
    else
      ln_final<<<512, 256, 0, stream>>>(x, x, lfg + i * 512, lfb + i * 512);
  }
}

// Round 16
// 1000.411 us; speedup vs baseline: 1.3201x; 1.1435x over previous
//
#include <hip/hip_runtime.h>
#include <math.h>

#define CC 512
#define NH 8
#define HD 64
#define TT 256

typedef __attribute__((ext_vector_type(8))) short short8v;
typedef __attribute__((ext_vector_type(4))) float f32x4;

__device__ inline unsigned short bfc(float f) {  // fp32 -> bf16, RNE
  unsigned u = __float_as_uint(f);
  return (unsigned short)((u + 0x7fffu + ((u >> 16) & 1u)) >> 16);
}
__device__ inline float b2f(unsigned short s) {
  return __uint_as_float((unsigned)s << 16);
}
// async global->LDS, 16B per lane; l must be the wave-uniform base.
__device__ inline void gld16(const void* g, void* l) {
  __builtin_amdgcn_global_load_lds(
      (const __attribute__((address_space(1))) unsigned int*)g,
      (__attribute__((address_space(3))) unsigned int*)l, 16, 0, 0);
}

// ---------------- prep: x=id_x; fb=bf16(frames); pb=bf16(id_prev) ------------
__global__ __launch_bounds__(256) void prep_k(const float* __restrict__ id_x,
    const float* __restrict__ frames, const float* __restrict__ id_prev,
    float* __restrict__ x, unsigned short* __restrict__ fb,
    unsigned short* __restrict__ pb) {
  int i = blockIdx.x * 256 + threadIdx.x;  // 0..1048575
  if (i < 262144) {
    ((float4*)x)[i] = ((const float4*)id_x)[i];
  } else if (i < 786432) {
    int j = i - 262144;
    float4 f = ((const float4*)frames)[j];
    ushort4 o; o.x = bfc(f.x); o.y = bfc(f.y); o.z = bfc(f.z); o.w = bfc(f.w);
    ((ushort4*)fb)[j] = o;
  } else {
    int j = i - 786432;
    float4 f = ((const float4*)id_prev)[j];
    ushort4 o; o.x = bfc(f.x); o.y = bfc(f.y); o.z = bfc(f.z); o.w = bfc(f.w);
    ((ushort4*)pb)[j] = o;
  }
}

// ---------------- LayerNorm: one WAVE per row (no LDS, no barriers) ----------
__global__ __launch_bounds__(256) void ln_bf(const float* __restrict__ in,
    unsigned short* __restrict__ out, const float* __restrict__ g, const float* __restrict__ b) {
  int row = (blockIdx.x << 2) + (threadIdx.x >> 6), lane = threadIdx.x & 63;
  const float* r = in + (size_t)row * CC;
  float4 v0 = *(const float4*)(r + (lane << 2));
  float4 v1 = *(const float4*)(r + 256 + (lane << 2));
  float s = v0.x + v0.y + v0.z + v0.w + v1.x + v1.y + v1.z + v1.w;
  #pragma unroll
  for (int o = 32; o; o >>= 1) s += __shfl_xor(s, o);
  float mu = s * (1.0f / CC);
  float d0x = v0.x - mu, d0y = v0.y - mu, d0z = v0.z - mu, d0w = v0.w - mu;
  float d1x = v1.x - mu, d1y = v1.y - mu, d1z = v1.z - mu, d1w = v1.w - mu;
  float sq = d0x*d0x + d0y*d0y + d0z*d0z + d0w*d0w + d1x*d1x + d1y*d1y + d1z*d1z + d1w*d1w;
  #pragma unroll
  for (int o = 32; o; o >>= 1) sq += __shfl_xor(sq, o);
  float inv = rsqrtf(sq * (1.0f / CC) + 1e-5f);
  float4 g0 = *(const float4*)(g + (lane << 2)), g1 = *(const float4*)(g + 256 + (lane << 2));
  float4 b0 = *(const float4*)(b + (lane << 2)), b1 = *(const float4*)(b + 256 + (lane << 2));
  ushort4 o0, o1;
  o0.x = bfc(d0x*inv*g0.x + b0.x); o0.y = bfc(d0y*inv*g0.y + b0.y);
  o0.z = bfc(d0z*inv*g0.z + b0.z); o0.w = bfc(d0w*inv*g0.w + b0.w);
  o1.x = bfc(d1x*inv*g1.x + b1.x); o1.y = bfc(d1y*inv*g1.y + b1.y);
  o1.z = bfc(d1z*inv*g1.z + b1.z); o1.w = bfc(d1w*inv*g1.w + b1.w);
  *(ushort4*)(out + (size_t)row * CC + (lane << 2)) = o0;
  *(ushort4*)(out + (size_t)row * CC + 256 + (lane << 2)) = o1;
}

__global__ __launch_bounds__(256) void ln_final(const float* __restrict__ in,
    float* __restrict__ out, const float* __restrict__ g, const float* __restrict__ b) {
  int row = (blockIdx.x << 2) + (threadIdx.x >> 6), lane = threadIdx.x & 63;
  const float* r = in + (size_t)row * CC;
  float4 v0 = *(const float4*)(r + (lane << 2));
  float4 v1 = *(const float4*)(r + 256 + (lane << 2));
  float s = v0.x + v0.y + v0.z + v0.w + v1.x + v1.y + v1.z + v1.w;
  #pragma unroll
  for (int o = 32; o; o >>= 1) s += __shfl_xor(s, o);
  float mu = s * (1.0f / CC);
  float d0x = v0.x - mu, d0y = v0.y - mu, d0z = v0.z - mu, d0w = v0.w - mu;
  float d1x = v1.x - mu, d1y = v1.y - mu, d1z = v1.z - mu, d1w = v1.w - mu;
  float sq = d0x*d0x + d0y*d0y + d0z*d0z + d0w*d0w + d1x*d1x + d1y*d1y + d1z*d1z + d1w*d1w;
  #pragma unroll
  for (int o = 32; o; o >>= 1) sq += __shfl_xor(sq, o);
  float inv = rsqrtf(sq * (1.0f / CC) + 1e-5f);
  float4 g0 = *(const float4*)(g + (lane << 2)), g1 = *(const float4*)(g + 256 + (lane << 2));
  float4 b0 = *(const float4*)(b + (lane << 2)), b1 = *(const float4*)(b + 256 + (lane << 2));
  float4 o0, o1;
  o0.x = d0x*inv*g0.x + b0.x; o0.y = d0y*inv*g0.y + b0.y;
  o0.z = d0z*inv*g0.z + b0.z; o0.w = d0w*inv*g0.w + b0.w;
  o1.x = d1x*inv*g1.x + b1.x; o1.y = d1y*inv*g1.y + b1.y;
  o1.z = d1z*inv*g1.z + b1.z; o1.w = d1w*inv*g1.w + b1.w;
  *(float4*)(out + (size_t)row * CC + (lane << 2)) = o0;
  *(float4*)(out + (size_t)row * CC + 256 + (lane << 2)) = o1;
}

// LNf then LN1-of-next-layer: x fp32, xb bf16, h bf16 — all wave-local
__global__ __launch_bounds__(256) void ln_chain(const float* __restrict__ in,
    float* __restrict__ xout, unsigned short* __restrict__ xb,
    const float* __restrict__ gf, const float* __restrict__ bf,
    const float* __restrict__ g1, const float* __restrict__ b1,
    unsigned short* __restrict__ hout) {
  int row = (blockIdx.x << 2) + (threadIdx.x >> 6), lane = threadIdx.x & 63;
  const float* r = in + (size_t)row * CC;
  float4 v0 = *(const float4*)(r + (lane << 2));
  float4 v1 = *(const float4*)(r + 256 + (lane << 2));
  float s = v0.x + v0.y + v0.z + v0.w + v1.x + v1.y + v1.z + v1.w;
  #pragma unroll
  for (int o = 32; o; o >>= 1) s += __shfl_xor(s, o);
  float mu = s * (1.0f / CC);
  float d0x = v0.x - mu, d0y = v0.y - mu, d0z = v0.z - mu, d0w = v0.w - mu;
  float d1x = v1.x - mu, d1y = v1.y - mu, d1z = v1.z - mu, d1w = v1.w - mu;
  float sq = d0x*d0x + d0y*d0y + d0z*d0z + d0w*d0w + d1x*d1x + d1y*d1y + d1z*d1z + d1w*d1w;
  #pragma unroll
  for (int o = 32; o; o >>= 1) sq += __shfl_xor(sq, o);
  float inv = rsqrtf(sq * (1.0f / CC) + 1e-5f);
  float4 g0 = *(const float4*)(gf + (lane << 2)), g1v = *(const float4*)(gf + 256 + (lane << 2));
  float4 b0 = *(const float4*)(bf + (lane << 2)), b1v = *(const float4*)(bf + 256 + (lane << 2));
  float4 x0, x1;
  x0.x = d0x*inv*g0.x + b0.x; x0.y = d0y*inv*g0.y + b0.y;
  x0.z = d0z*inv*g0.z + b0.z; x0.w = d0w*inv*g0.w + b0.w;
  x1.x = d1x*inv*g1v.x + b1v.x; x1.y = d1y*inv*g1v.y + b1v.y;
  x1.z = d1z*inv*g1v.z + b1v.z; x1.w = d1w*inv*g1v.w + b1v.w;
  *(float4*)(xout + (size_t)row * CC + (lane << 2)) = x0;
  *(float4*)(xout + (size_t)row * CC + 256 + (lane << 2)) = x1;
  ushort4 xb0, xb1;
  xb0.x = bfc(x0.x); xb0.y = bfc(x0.y); xb0.z = bfc(x0.z); xb0.w = bfc(x0.w);
  xb1.x = bfc(x1.x); xb1.y = bfc(x1.y); xb1.z = bfc(x1.z); xb1.w = bfc(x1.w);
  *(ushort4*)(xb + (size_t)row * CC + (lane << 2)) = xb0;
  *(ushort4*)(xb + (size_t)row * CC + 256 + (lane << 2)) = xb1;
  // second LN
  float s2 = x0.x + x0.y + x0.z + x0.w + x1.x + x1.y + x1.z + x1.w;
  #pragma unroll
  for (int o = 32; o; o >>= 1) s2 += __shfl_xor(s2, o);
  float mu2 = s2 * (1.0f / CC);
  float e0x = x0.x - mu2, e0y = x0.y - mu2, e0z = x0.z - mu2, e0w = x0.w - mu2;
  float e1x = x1.x - mu2, e1y = x1.y - mu2, e1z = x1.z - mu2, e1w = x1.w - mu2;
  float sq2 = e0x*e0x + e0y*e0y + e0z*e0z + e0w*e0w + e1x*e1x + e1y*e1y + e1z*e1z + e1w*e1w;
  #pragma unroll
  for (int o = 32; o; o >>= 1) sq2 += __shfl_xor(sq2, o);
  float inv2 = rsqrtf(sq2 * (1.0f / CC) + 1e-5f);
  float4 h0 = *(const float4*)(g1 + (lane << 2)), h1 = *(const float4*)(g1 + 256 + (lane << 2));
  float4 c0 = *(const float4*)(b1 + (lane << 2)), c1 = *(const float4*)(b1 + 256 + (lane << 2));
  ushort4 ho0, ho1;
  ho0.x = bfc(e0x*inv2*h0.x + c0.x); ho0.y = bfc(e0y*inv2*h0.y + c0.y);
  ho0.z = bfc(e0z*inv2*h0.z + c0.z); ho0.w = bfc(e0w*inv2*h0.w + c0.w);
  ho1.x = bfc(e1x*inv2*h1.x + c1.x); ho1.y = bfc(e1y*inv2*h1.y + c1.y);
  ho1.z = bfc(e1z*inv2*h1.z + c1.z); ho1.w = bfc(e1w*inv2*h1.w + c1.w);
  *(ushort4*)(hout + (size_t)row * CC + (lane << 2)) = ho0;
  *(ushort4*)(hout + (size_t)row * CC + 256 + (lane << 2)) = ho1;
}

// ---------------- weight transpose+convert: W[K][N] fp32 -> WT[N][K] bf16 -----
__global__ __launch_bounds__(256) void transpose_w(
    const float* __restrict__ Wq, const float* __restrict__ Wk,
    const float* __restrict__ Wv, const float* __restrict__ Wo,
    const float* __restrict__ W1, const float* __restrict__ W2,
    int layer_base, unsigned short* __restrict__ wT) {
  int lz = blockIdx.x / 3072;
  int layer = layer_base + lz;
  int bid = blockIdx.x - lz * 3072;
  unsigned short* wTl = wT + (size_t)lz * 3145728;
  const float* src; unsigned short* dst; int R, Cn, tile, lg;
  if (bid < 1024) {
    int seg = bid >> 8; tile = bid & 255; R = 512; Cn = 512; lg = 4;
    const float* s4[4] = {Wq, Wk, Wv, Wo};
    src = s4[seg] + (size_t)layer * 262144;
    dst = wTl + (size_t)seg * 262144;
  } else if (bid < 2048) {
    tile = bid - 1024; R = 512; Cn = 2048; lg = 6;
    src = W1 + (size_t)layer * 1048576; dst = wTl + 1048576;
  } else {
    tile = bid - 2048; R = 2048; Cn = 512; lg = 4;
    src = W2 + (size_t)layer * 1048576; dst = wTl + 2097152;
  }
  int trb = tile >> lg, tcb = tile & ((1 << lg) - 1);
  __shared__ float tl[32][33];
  int t = threadIdx.x;
  int r = t >> 3, c4 = (t & 7) << 2;
  const float* sp = src + (size_t)(trb * 32 + r) * Cn + tcb * 32 + c4;
  float4 fv = *(const float4*)sp;
  tl[r][c4] = fv.x; tl[r][c4 + 1] = fv.y; tl[r][c4 + 2] = fv.z; tl[r][c4 + 3] = fv.w;
  __syncthreads();
  unsigned short* dp = dst + (size_t)(tcb * 32 + r) * R + trb * 32 + c4;
  ushort4 ov;
  ov.x = bfc(tl[c4][r]); ov.y = bfc(tl[c4 + 1][r]);
  ov.z = bfc(tl[c4 + 2][r]); ov.w = bfc(tl[c4 + 3][r]);
  *(ushort4*)dp = ov;
}

// ---------------- bf16 MFMA GEMM with global_load_lds staging ----------------
template<int BM, int GELU, int RES, int OUTBF, int BIAS2, int QSC>
__global__ __launch_bounds__(256) void gemm_bf(
    const unsigned short* __restrict__ A, const unsigned short* __restrict__ WT,
    const float* __restrict__ bias, const float* __restrict__ bias2,
    void* __restrict__ outp, const float* __restrict__ res, int M, int N, int K) {
  __shared__ __align__(16) unsigned short As[BM * 64];
  __shared__ __align__(16) unsigned short Bs[64 * 64];
  const int tid = threadIdx.x, lane = tid & 63, wid = tid >> 6;
  const int bm = blockIdx.y * BM, bn = blockIdx.x << 6;
  const int wm = (wid >> 1) * (BM / 2), wn = (wid & 1) << 5;
  constexpr int MF = BM / 32;
  f32x4 acc[MF][2] = {};
  const int fr = lane & 15, fq = lane >> 4;
  for (int k0 = 0; k0 < K; k0 += 64) {
    if (k0) __syncthreads();
    #pragma unroll
    for (int i = 0; i < BM / 32; i++) {
      int gl = tid + (i << 8);
      int row = gl >> 3, gc = gl & 7;
      int gcs = gc ^ (row & 7);
      gld16(A + (size_t)(bm + row) * K + k0 + (gcs << 3),
            (char*)As + (i << 12) + (wid << 10));
    }
    #pragma unroll
    for (int i = 0; i < 2; i++) {
      int gl = tid + (i << 8);
      int row = gl >> 3, gc = gl & 7;
      int gcs = gc ^ (row & 7);
      gld16(WT + (size_t)(bn + row) * K + k0 + (gcs << 3),
            (char*)Bs + (i << 12) + (wid << 10));
    }
    __syncthreads();
    short8v af[MF][2], bf2[2][2];
    #pragma unroll
    for (int mf = 0; mf < MF; mf++)
      #pragma unroll
      for (int ks = 0; ks < 2; ks++) {
        int r = wm + mf * 16 + fr;
        int c = (ks << 2) + fq;
        af[mf][ks] = *(const short8v*)((const char*)As + ((((r << 7) + (c << 4))) ^ ((r & 7) << 4)));
      }
    #pragma unroll
    for (int nf = 0; nf < 2; nf++)
      #pragma unroll
      for (int ks = 0; ks < 2; ks++) {
        int r = wn + nf * 16 + fr;
        int c = (ks << 2) + fq;
        bf2[nf][ks] = *(const short8v*)((const char*)Bs + ((((r << 7) + (c << 4))) ^ ((r & 7) << 4)));
      }
    #pragma unroll
    for (int mf = 0; mf < MF; mf++)
      #pragma unroll
      for (int nf = 0; nf < 2; nf++) {
        acc[mf][nf] = __builtin_amdgcn_mfma_f32_16x16x32_bf16(af[mf][0], bf2[nf][0], acc[mf][nf], 0, 0, 0);
        acc[mf][nf] = __builtin_amdgcn_mfma_f32_16x16x32_bf16(af[mf][1], bf2[nf][1], acc[mf][nf], 0, 0, 0);
      }
  }
  #pragma unroll
  for (int mf = 0; mf < MF; mf++)
    #pragma unroll
    for (int nf = 0; nf < 2; nf++) {
      int col = bn + wn + nf * 16 + fr;
      float bia = (BIAS2 && col >= 512) ? bias2[col - 512] : bias[col];
      #pragma unroll
      for (int rr = 0; rr < 4; rr++) {
        int row = bm + wm + mf * 16 + fq * 4 + rr;
        float vv = acc[mf][nf][rr] + bia;
        if (GELU) vv = 0.5f * vv * (1.0f + erff(vv * 0.70710678118654752f));
        if (RES)  vv += res[(size_t)row * N + col];
        if (QSC)  vv *= 0.125f;
        if (OUTBF) ((unsigned short*)outp)[(size_t)row * N + col] = bfc(vv);
        else       ((float*)outp)[(size_t)row * N + col] = vv;
      }
    }
}

// ---------------- MFMA attention: 8 q-rows/block, 8 waves, 1 row/wave --------
template<int CAUSAL, int TOPK, int TSK>
__global__ __launch_bounds__(512, 4) void attn_m(
    const unsigned short* __restrict__ qb, const unsigned short* __restrict__ kv,
    unsigned short* __restrict__ yb) {
  constexpr int NT = TSK / 64;
  constexpr int NKC = TSK / 128;
  constexpr int SST = TSK + 8;
  __shared__ float S[8 * SST];
  __shared__ __align__(16) unsigned short Ks[128 * 64];  // 16KB
  __shared__ __align__(16) unsigned short Qs[16 * 64];   // 2KB (rows 8-15 zero)
  __shared__ float swt[TOPK ? 8 : 1][TOPK ? 128 : 1];
  __shared__ unsigned short kidx[TOPK ? 8 : 1][TOPK ? 128 : 1];
  int tid = threadIdx.x, lane = tid & 63, wid = tid >> 6;
  int bid = blockIdx.x;
  int swz = ((bid & 7) << 8) | (bid >> 3);  // 2048 blocks, bijective XCD swizzle
  int b = swz >> 8, h = (swz >> 5) & 7, q0 = (swz & 31) << 3;
  if (tid < 64) {
    int row = tid >> 3, sp = tid & 7;
    gld16(qb + (size_t)((b << 8) + q0 + row) * CC + (h << 6) + ((sp ^ (row & 7)) << 3),
          (char*)Qs);
  } else if (tid < 128) {
    short8v z = {0, 0, 0, 0, 0, 0, 0, 0};
    *(short8v*)((char*)Qs + (tid << 4)) = z;
  }
  __syncthreads();
  short8v aF[2];
  {
    int r = lane & 15, kq2 = lane >> 4;
    #pragma unroll
    for (int kc2 = 0; kc2 < 2; kc2++)
      aF[kc2] = *(const short8v*)((const char*)Qs +
                 (((r << 7) + (kc2 << 6) + (kq2 << 4)) ^ ((r & 7) << 4)));
  }
  int nte = NKC;
  if (CAUSAL) { int ub = (q0 + 8 + 127) >> 7; nte = ub < NKC ? ub : NKC; }
  const unsigned short* kgb = kv + (size_t)b * TSK * 1024 + (h << 6);
  for (int t = 0; t < nte; t++) {
    __syncthreads();
    #pragma unroll
    for (int j = 0; j < 2; j++) {
      int s = (wid << 7) + (j << 6) + lane;
      int row = s >> 3, sp = s & 7;
      gld16(kgb + (size_t)((t << 7) + row) * 1024 + ((sp ^ (row & 7)) << 3),
            (char*)Ks + (wid << 11) + (j << 10));
    }
    __syncthreads();
    int kq2 = lane >> 4;
    f32x4 acc = {};
    int key16 = (wid << 4) + (lane & 15);
    #pragma unroll
    for (int kc2 = 0; kc2 < 2; kc2++) {
      short8v bF = *(const short8v*)((const char*)Ks +
                    (((key16 << 7) + (kc2 << 6) + (kq2 << 4)) ^ ((key16 & 7) << 4)));
      acc = __builtin_amdgcn_mfma_f32_16x16x32_bf16(aF[kc2], bF, acc, 0, 0, 0);
    }
    if (kq2 < 2) {  // rows 0-7 live in fq 0,1
      int col = (t << 7) + key16;
      #pragma unroll
      for (int r = 0; r < 4; r++)
        S[(kq2 * 4 + r) * SST + col] = acc[r];
    }
  }
  __syncthreads();
  int row = wid;
  int qi = q0 + row;
  int jmax = CAUSAL ? (qi + 1) : TSK;
  const unsigned short* vgb = kv + (size_t)b * TSK * 1024 + 512 + (h << 6) + lane;
  float sc[NT];
  float lmax = -3.0e38f;
  #pragma unroll
  for (int tt = 0; tt < NT; tt++) {
    int key = lane + (tt << 6);
    float v = (!CAUSAL || key < jmax) ? S[row * SST + key] : -3.0e38f;
    sc[tt] = v;
    lmax = fmaxf(lmax, v);
  }
  float mx = lmax;
  #pragma unroll
  for (int o = 32; o; o >>= 1) mx = fmaxf(mx, __shfl_xor(mx, o));
  float oacc = 0.f;
  if (TOPK) {
    unsigned key[NT];
    #pragma unroll
    for (int tt = 0; tt < NT; tt++) {
      unsigned u = __float_as_uint(sc[tt]);
      key[tt] = (u & 0x80000000u) ? ~u : (u | 0x80000000u);
    }
    unsigned prefix = 0u;
    for (int bit = 31; bit >= 0; bit--) {   // early exit when kept set exact
      unsigned cand = prefix | (1u << bit);
      int cnt = 0;
      #pragma unroll
      for (int tt = 0; tt < NT; tt++)
        cnt += __popcll(__ballot(key[tt] >= cand));
      if (cnt >= 64) {
        prefix = cand;
        if (cnt == 64) break;
      }
    }
    float wvv[NT];
    float psum = 0.f;
    int basec = 0;
    #pragma unroll
    for (int tt = 0; tt < NT; tt++) {
      bool keep = key[tt] >= prefix;
      float wv = keep ? exp2f((sc[tt] - mx) * 1.4426950408889634f) : 0.f;
      wvv[tt] = wv;
      psum += wv;
      unsigned long long mask = __ballot(keep);
      if (keep) {
        int pos = basec + (int)__popcll(mask & ((1ull << lane) - 1ull));
        if (pos < 128) {
          kidx[row][pos] = (unsigned short)(lane + (tt << 6));
          swt[row][pos] = wv;
        }
      }
      basec += (int)__popcll(mask);
    }
    #pragma unroll
    for (int o = 32; o; o >>= 1) psum += __shfl_xor(psum, o);
    float inv = 1.0f / psum;
    int nk = basec;
    if (nk <= 128) {
      float a0 = 0.f, a1 = 0.f, a2 = 0.f, a3 = 0.f;
      int i = 0;
      for (; i + 3 < nk; i += 4) {
        a0 += swt[row][i]     * b2f(vgb[(size_t)kidx[row][i] * 1024]);
        a1 += swt[row][i + 1] * b2f(vgb[(size_t)kidx[row][i + 1] * 1024]);
        a2 += swt[row][i + 2] * b2f(vgb[(size_t)kidx[row][i + 2] * 1024]);
        a3 += swt[row][i + 3] * b2f(vgb[(size_t)kidx[row][i + 3] * 1024]);
      }
      for (; i < nk; i++) a0 += swt[row][i] * b2f(vgb[(size_t)kidx[row][i] * 1024]);
      oacc = (a0 + a1 + a2 + a3) * inv;
    } else {  // pathological tie overflow: full scan via S
      #pragma unroll
      for (int tt = 0; tt < NT; tt++)
        S[row * SST + lane + (tt << 6)] = wvv[tt];
      float a0 = 0.f, a1 = 0.f;
      for (int j = 0; j + 1 < TSK; j += 2) {
        a0 += S[row * SST + j]     * b2f(vgb[(size_t)j * 1024]);
        a1 += S[row * SST + j + 1] * b2f(vgb[(size_t)(j + 1) * 1024]);
      }
      oacc = (a0 + a1) * inv;
    }
  } else {
    float psum = 0.f;
    #pragma unroll
    for (int tt = 0; tt < NT; tt++) {
      int keyj = lane + (tt << 6);
      float wv = (keyj < jmax) ? exp2f((sc[tt] - mx) * 1.4426950408889634f) : 0.f;
      S[row * SST + keyj] = wv;
      psum += wv;
    }
    #pragma unroll
    for (int o = 32; o; o >>= 1) psum += __shfl_xor(psum, o);
    float inv = 1.0f / psum;
    float a0 = 0.f, a1 = 0.f, a2 = 0.f, a3 = 0.f;
    int j = 0;
    for (; j + 3 < jmax; j += 4) {
      a0 += S[row * SST + j]     * b2f(vgb[(size_t)j * 1024]);
      a1 += S[row * SST + j + 1] * b2f(vgb[(size_t)(j + 1) * 1024]);
      a2 += S[row * SST + j + 2] * b2f(vgb[(size_t)(j + 2) * 1024]);
      a3 += S[row * SST + j + 3] * b2f(vgb[(size_t)(j + 3) * 1024]);
    }
    for (; j < jmax; j++) a0 += S[row * SST + j] * b2f(vgb[(size_t)j * 1024]);
    oacc = (a0 + a1 + a2 + a3) * inv;
  }
  yb[(size_t)((b << 8) + qi) * CC + (h << 6) + lane] = bfc(oacc);
}

extern "C" void kernel_launch(void* const* d_in, const int* in_sizes, int n_in,
                              void* d_out, int out_size, void* d_ws, size_t ws_size,
                              hipStream_t stream) {
  const float* id_x    = (const float*)d_in[0];
  const float* id_prev = (const float*)d_in[1];
  const float* frames  = (const float*)d_in[2];
  const float* Wq = (const float*)d_in[3];  const float* bq = (const float*)d_in[4];
  const float* Wk = (const float*)d_in[5];  const float* bk = (const float*)d_in[6];
  const float* Wv = (const float*)d_in[7];  const float* bv = (const float*)d_in[8];
  const float* Wo = (const float*)d_in[9];  const float* bo = (const float*)d_in[10];
  const float* W1 = (const float*)d_in[11]; const float* b1 = (const float*)d_in[12];
  const float* W2 = (const float*)d_in[13]; const float* b2 = (const float*)d_in[14];
  const float* l1g = (const float*)d_in[15]; const float* l1b = (const float*)d_in[16];
  const float* l2g = (const float*)d_in[17]; const float* l2b = (const float*)d_in[18];
  const float* lfg = (const float*)d_in[19]; const float* lfb = (const float*)d_in[20];

  float* x = (float*)d_out;
  char* W  = (char*)d_ws;
  unsigned short* qbuf = (unsigned short*)W;                        // 2MB bf16 q (pre-scaled)
  unsigned short* kvb  = (unsigned short*)(W + ((size_t)4  << 20)); // 8MB packed K|V
  unsigned short* m1b  = (unsigned short*)(W + ((size_t)4  << 20)); // 8MB, alias kv
  unsigned short* hb   = (unsigned short*)(W + ((size_t)12 << 20)); // 2MB
  unsigned short* ybf  = (unsigned short*)(W + ((size_t)14 << 20)); // 2MB
  unsigned short* xb   = (unsigned short*)(W + ((size_t)16 << 20)); // 2MB
  unsigned short* fb   = (unsigned short*)(W + ((size_t)18 << 20)); // 4MB
  unsigned short* pb   = (unsigned short*)(W + ((size_t)22 << 20)); // 2MB
  unsigned short* wT   = (unsigned short*)(W + ((size_t)24 << 20)); // 6MB or 60MB

  const bool allw = ws_size >= (((size_t)24 << 20) + (size_t)10 * 3145728 * 2);

  prep_k<<<4096, 256, 0, stream>>>(id_x, frames, id_prev, x, fb, pb);
  if (allw)
    transpose_w<<<30720, 256, 0, stream>>>(Wq, Wk, Wv, Wo, W1, W2, 0, wT);

  static const int ssrc[10] = {0, 0, 0, 0, 1, 1, 2, 2, 1, 1};

  for (int i = 0; i < 10; i++) {
    if (!allw)
      transpose_w<<<3072, 256, 0, stream>>>(Wq, Wk, Wv, Wo, W1, W2, i, wT);
    unsigned short* wTl = wT + (allw ? (size_t)i * 3145728 : 0);
    unsigned short* wqT = wTl;
    unsigned short* wkvT = wTl + 262144;   // [1024][512]: K rows then V rows
    unsigned short* woT = wTl + 786432;
    unsigned short* w1T = wTl + 1048576;
    unsigned short* w2T = wTl + 2097152;

    if (i == 0)
      ln_bf<<<512, 256, 0, stream>>>(x, hb, l1g, l1b);

    // q = (LN1(x) @ Wq + bq) * 0.125 (bf16, pre-scaled for attention)
    gemm_bf<32, 0, 0, 1, 0, 1><<<dim3(8, 64), 256, 0, stream>>>(hb, wqT, bq + i * 512, nullptr, qbuf, nullptr, 2048, 512, 512);

    // kv = src @ [Wk|Wv] + [bk|bv]  (bf16, packed row stride 1024)
    const unsigned short* kvsrc; int Mkv;
    if (ssrc[i] == 0)      { kvsrc = fb; Mkv = 4096; }
    else if (ssrc[i] == 1) { kvsrc = xb; Mkv = 2048; }
    else                   { kvsrc = pb; Mkv = 2048; }
    if (Mkv == 4096)
      gemm_bf<64, 0, 0, 1, 1, 0><<<dim3(16, 64), 256, 0, stream>>>(kvsrc, wkvT, bk + i * 512, bv + i * 512, kvb, nullptr, 4096, 1024, 512);
    else
      gemm_bf<32, 0, 0, 1, 1, 0><<<dim3(16, 64), 256, 0, stream>>>(kvsrc, wkvT, bk + i * 512, bv + i * 512, kvb, nullptr, 2048, 1024, 512);

    if (ssrc[i] == 0)      attn_m<0, 1, 512><<<2048, 512, 0, stream>>>(qbuf, kvb, ybf);
    else if (ssrc[i] == 1) attn_m<1, 0, 256><<<2048, 512, 0, stream>>>(qbuf, kvb, ybf);
    else                   attn_m<0, 0, 256><<<2048, 512, 0, stream>>>(qbuf, kvb, ybf);

    // x = x + y @ Wo + bo
    gemm_bf<32, 0, 1, 0, 0, 0><<<dim3(8, 64), 256, 0, stream>>>(ybf, woT, bo + i * 512, nullptr, x, x, 2048, 512, 512);
    // h = LN2(x) bf16
    ln_bf<<<512, 256, 0, stream>>>(x, hb, l2g + i * 512, l2b + i * 512);
    // m1 = gelu(h @ W1 + b1) bf16
    gemm_bf<64, 1, 0, 1, 0, 0><<<dim3(32, 32), 256, 0, stream>>>(hb, w1T, b1 + i * 2048, nullptr, m1b, nullptr, 2048, 2048, 512);
    // x = x + m1 @ W2 + b2
    gemm_bf<32, 0, 1, 0, 0, 0><<<dim3(8, 64), 256, 0, stream>>>(m1b, w2T, b2 + i * 512, nullptr, x, x, 2048, 512, 2048);

    if (i < 9)
      ln_chain<<<512, 256, 0, stream>>>(x, x, xb, lfg + i * 512, lfb + i * 512,
                                        l1g + (i + 1) * 512, l1b + (i + 1) * 512, hb);
    else
      ln_final<<<512, 256, 0, stream>>>(x, x, lfg + i * 512, lfb + i * 512);
  }
}